// Round 25
// baseline (481.192 us; speedup 1.0000x reference)
//
#include <hip/hip_runtime.h>
#include <math.h>

typedef unsigned short u16;
typedef __attribute__((ext_vector_type(8))) short bf16x8;
typedef __attribute__((ext_vector_type(4))) float f32x4;

__device__ __forceinline__ u16 f2bf(float x) {
    union { float f; unsigned int u; } c; c.f = x;
    unsigned int r = c.u + 0x7fffu + ((c.u >> 16) & 1u);
    return (u16)(r >> 16);
}
__device__ __forceinline__ float bf2f(u16 h) {
    union { unsigned int u; float f; } c; c.u = ((unsigned int)h) << 16;
    return c.f;
}
__device__ __forceinline__ bf16x8 ld16(const u16* p) {
    bf16x8 r;
    ((uint2*)&r)[0] = *(const uint2*)p;
    ((uint2*)&r)[1] = *(const uint2*)(p + 4);
    return r;
}
__device__ __forceinline__ void st8(u16* dst, uint4 r) {
    *(uint2*)dst = make_uint2(r.x, r.y);
    *(uint2*)(dst + 4) = make_uint2(r.z, r.w);
}
__device__ __forceinline__ void cvt8(const float4& v0, const float4& v1,
                                     uint4& hi, uint4& lo) {
    float vv[8] = {v0.x, v0.y, v0.z, v0.w, v1.x, v1.y, v1.z, v1.w};
    u16 h[8], l[8];
#pragma unroll
    for (int e = 0; e < 8; ++e) {
        h[e] = f2bf(vv[e]);
        l[e] = f2bf(vv[e] - bf2f(h[e]));
    }
    hi.x = h[0] | ((unsigned)h[1] << 16); hi.y = h[2] | ((unsigned)h[3] << 16);
    hi.z = h[4] | ((unsigned)h[5] << 16); hi.w = h[6] | ((unsigned)h[7] << 16);
    lo.x = l[0] | ((unsigned)l[1] << 16); lo.y = l[2] | ((unsigned)l[3] << 16);
    lo.z = l[4] | ((unsigned)l[5] << 16); lo.w = l[6] | ((unsigned)l[7] << 16);
}

// ---------------- gj body: scalar GJ, 1024 thr, 1 barrier/pivot ------------
__device__ void gj_body(const float* __restrict__ A, float* __restrict__ out,
                        int N, float (*rowbuf)[128], int tid) {
    const int i = tid >> 3, g = tid & 7, c0 = g * 16;
    const int rl = (i & 7) << 3;
    float r[16];
#pragma unroll
    for (int e = 0; e < 16; ++e) {
        int j = c0 + e;
        r[e] = (i < N && j < N) ? A[i * N + j] : ((i == j) ? 1.0f : 0.0f);
    }
    if (i == 0) {
        float ip = 1.0f / __shfl(r[0], rl, 64);
#pragma unroll
        for (int e = 0; e < 16; ++e)
            rowbuf[0][c0 + e] = (c0 + e == 0) ? ip : r[e] * ip;
    }
    __syncthreads();
    const int ng = N >> 4;
    for (int k16 = 0; k16 < ng; ++k16) {
#pragma unroll
        for (int e = 0; e < 16; ++e) {
            const int k = (k16 << 4) + e;
            const int pb = k & 1;
            float ci = __shfl(r[e], rl + k16, 64);
            float4 rb0 = *(const float4*)&rowbuf[pb][c0];
            float4 rb1 = *(const float4*)&rowbuf[pb][c0 + 4];
            float4 rb2 = *(const float4*)&rowbuf[pb][c0 + 8];
            float4 rb3 = *(const float4*)&rowbuf[pb][c0 + 12];
            float rb[16] = {rb0.x, rb0.y, rb0.z, rb0.w, rb1.x, rb1.y, rb1.z, rb1.w,
                            rb2.x, rb2.y, rb2.z, rb2.w, rb3.x, rb3.y, rb3.z, rb3.w};
            if (i == k) {
#pragma unroll
                for (int e2 = 0; e2 < 16; ++e2) r[e2] = rb[e2];
            } else {
#pragma unroll
                for (int e2 = 0; e2 < 16; ++e2) {
                    float v = (c0 + e2 == k) ? 0.0f : r[e2];
                    r[e2] = fmaf(-ci, rb[e2], v);
                }
            }
            if (k + 1 < N && i == k + 1) {
                const int en = (e + 1) & 15;
                const int gn = (e == 15) ? k16 + 1 : k16;
                float ip = 1.0f / __shfl(r[en], rl + gn, 64);
#pragma unroll
                for (int e2 = 0; e2 < 16; ++e2)
                    rowbuf[pb ^ 1][c0 + e2] = (c0 + e2 == k + 1) ? ip : r[e2] * ip;
            }
            __syncthreads();
        }
    }
    if (i < N)
#pragma unroll
        for (int e = 0; e < 16; ++e) {
            int j = c0 + e;
            if (j < N) out[i * N + j] = r[e];
        }
}

// ---------------- kron body: 4 rows/block, kron-256 arithmetic per group ---
template <int TA, int TB, int OUTQ, int DIV>
__device__ void kron4_body(const float* __restrict__ X, const float* __restrict__ scIn,
                           const float* __restrict__ A, const float* __restrict__ B,
                           u16* __restrict__ Yq, float* __restrict__ Ysc,
                           float* __restrict__ Yf, int row0, int tid,
                           float* Al, float* Bl, float (*Tl)[32 * 65], float* red) {
    {
        int c = tid >> 5, a = tid & 31;
        Al[c * 33 + a] = TA ? A[a * 32 + c] : A[c * 32 + a];
    }
    for (int idx = tid; idx < 4096; idx += 1024) {
        int d = idx >> 6, b = idx & 63;
        Bl[d * 65 + b] = TB ? B[b * 64 + d] : B[d * 64 + b];
    }
    __syncthreads();

    const int g = tid >> 8, t = tid & 255;
    const int row = row0 + g;
    const int c = t >> 3, b0 = (t & 7) * 8;

    const float* xp = X + (size_t)row * 2048 + c * 64;
    const float* sp = scIn + c * 64;
    float tacc[8];
#pragma unroll
    for (int jj = 0; jj < 8; ++jj) tacc[jj] = 0.0f;
    for (int d0 = 0; d0 < 64; d0 += 4) {
        float4 xv4 = *(const float4*)(xp + d0);
        float4 sc4 = *(const float4*)(sp + d0);
        float xs4[4];
        if (DIV) {
            xs4[0] = xv4.x * (1.0f / sc4.x); xs4[1] = xv4.y * (1.0f / sc4.y);
            xs4[2] = xv4.z * (1.0f / sc4.z); xs4[3] = xv4.w * (1.0f / sc4.w);
        } else {
            xs4[0] = xv4.x * sc4.x; xs4[1] = xv4.y * sc4.y;
            xs4[2] = xv4.z * sc4.z; xs4[3] = xv4.w * sc4.w;
        }
#pragma unroll
        for (int e = 0; e < 4; ++e) {
            float xv = xs4[e];
#pragma unroll
            for (int jj = 0; jj < 8; ++jj)
                tacc[jj] = fmaf(xv, Bl[(d0 + e) * 65 + b0 + jj], tacc[jj]);
        }
    }
#pragma unroll
    for (int jj = 0; jj < 8; ++jj) Tl[g][c * 65 + b0 + jj] = tacc[jj];
    __syncthreads();

    const int a = t >> 3;
    float y[8];
#pragma unroll
    for (int jj = 0; jj < 8; ++jj) y[jj] = 0.0f;
    for (int c2 = 0; c2 < 32; ++c2) {
        float av = Al[c2 * 33 + a];
#pragma unroll
        for (int jj = 0; jj < 8; ++jj)
            y[jj] = fmaf(av, Tl[g][c2 * 65 + b0 + jj], y[jj]);
    }

    if (OUTQ) {
        float am = 0.0f;
#pragma unroll
        for (int jj = 0; jj < 8; ++jj) am = fmaxf(am, fabsf(y[jj]));
        red[tid] = am;
        __syncthreads();
        for (int s = 128; s > 0; s >>= 1) {
            if (t < s) red[tid] = fmaxf(red[tid], red[tid + s]);
            __syncthreads();
        }
        float scale = fmaxf(red[g << 8] / 127.0f, 1e-8f);
        if (t == 0) Ysc[row] = scale;
        u16 qq[8];
#pragma unroll
        for (int e = 0; e < 8; ++e) {
            float v = rintf(y[e] / scale);
            v = fminf(fmaxf(v, -127.0f), 127.0f);
            qq[e] = f2bf(v);
        }
        uint4 pk;
        pk.x = qq[0] | ((unsigned)qq[1] << 16); pk.y = qq[2] | ((unsigned)qq[3] << 16);
        pk.z = qq[4] | ((unsigned)qq[5] << 16); pk.w = qq[6] | ((unsigned)qq[7] << 16);
        *(uint4*)(Yq + (size_t)row * 2048 + t * 8) = pk;
    } else {
        float* yp = Yf + (size_t)row * 2048 + t * 8;
        *(float4*)yp = make_float4(y[0], y[1], y[2], y[3]);
        *(float4*)(yp + 4) = make_float4(y[4], y[5], y[6], y[7]);
    }
}

// ---------------- transpose-split body (128x128) ---------------------------
__device__ void tsplit_body(const float* __restrict__ in, u16* __restrict__ hi,
                            u16* __restrict__ lo, int tid) {
    for (int idx = tid; idx < 16384; idx += 1024) {
        int r = idx >> 7, c = idx & 127;
        float v = in[r * 128 + c];
        u16 h = f2bf(v);
        hi[c * 128 + r] = h;
        lo[c * 128 + r] = f2bf(v - bf2f(h));
    }
}

// ---------------- P0a: gj(L), gj(R), kron(hidden), TkT/TvT transposes ------
__global__ __launch_bounds__(1024) void p0a_kernel(
    const float* __restrict__ Lp, float* __restrict__ invL,
    const float* __restrict__ Rp, float* __restrict__ invR,
    const float* __restrict__ hidden, const float* __restrict__ dg,
    u16* __restrict__ Xi, float* __restrict__ xs,
    const float* __restrict__ Tkp, u16* __restrict__ TkT_sh, u16* __restrict__ TkT_sl,
    const float* __restrict__ Tvp, u16* __restrict__ TvT_sh, u16* __restrict__ TvT_sl) {
    __shared__ float rowbuf[2][128];
    __shared__ float Al[32 * 33];
    __shared__ float Bl[64 * 65];
    __shared__ float Tl[4][32 * 65];
    __shared__ float red[1024];
    const int tid = threadIdx.x;
    const int b = blockIdx.x;
    if (b == 0) {
        gj_body(Lp, invL, 32, rowbuf, tid);
    } else if (b == 1) {
        gj_body(Rp, invR, 64, rowbuf, tid);
    } else if (b < 514) {
        kron4_body<0, 0, 1, 0>(hidden, dg, Lp, Rp, Xi, xs, 0, (b - 2) * 4, tid,
                               Al, Bl, Tl, red);
    } else if (b == 514) {
        tsplit_body(Tkp, TkT_sh, TkT_sl, tid);
    } else {
        tsplit_body(Tvp, TvT_sh, TvT_sl, tid);
    }
}

// ---------------- P0b: gj(Tk), gj(Tv), weight krons ------------------------
__global__ __launch_bounds__(1024) void p0b_kernel(
    const float* __restrict__ Tkp, float* __restrict__ invTk,
    const float* __restrict__ Tvp, float* __restrict__ invTv,
    const float* __restrict__ Wq, const float* __restrict__ Wk,
    const float* __restrict__ Wv, const float* __restrict__ dg,
    const float* __restrict__ invL, const float* __restrict__ invR,
    u16* __restrict__ WQi, float* __restrict__ wqs,
    u16* __restrict__ WKi, float* __restrict__ wks,
    float* __restrict__ WvP) {
    __shared__ float rowbuf[2][128];
    __shared__ float Al[32 * 33];
    __shared__ float Bl[64 * 65];
    __shared__ float Tl[4][32 * 65];
    __shared__ float red[1024];
    const int tid = threadIdx.x;
    const int b = blockIdx.x;
    if (b == 0) {
        gj_body(Tkp, invTk, 128, rowbuf, tid);
    } else if (b == 1) {
        gj_body(Tvp, invTv, 128, rowbuf, tid);
    } else if (b < 514) {
        kron4_body<1, 1, 1, 1>(Wq, dg, invL, invR, WQi, wqs, 0, (b - 2) * 4, tid,
                               Al, Bl, Tl, red);
    } else if (b < 770) {
        kron4_body<1, 1, 1, 1>(Wk, dg, invL, invR, WKi, wks, 0, (b - 514) * 4, tid,
                               Al, Bl, Tl, red);
    } else {
        kron4_body<1, 1, 0, 1>(Wv, dg, invL, invR, 0, 0, WvP, (b - 770) * 4, tid,
                               Al, Bl, Tl, red);
    }
}

// ---------------- ps: split(invTk) + transpose-split(invTv) ----------------
__global__ __launch_bounds__(1024) void ps_kernel(
    const float* __restrict__ invTk, u16* __restrict__ ik_h, u16* __restrict__ ik_l,
    const float* __restrict__ invTv, u16* __restrict__ ivT_h, u16* __restrict__ ivT_l) {
    const int tid = threadIdx.x;
    if (blockIdx.x == 0) {
        for (int idx = tid; idx < 16384; idx += 1024) {
            float v = invTk[idx];
            u16 h = f2bf(v);
            ik_h[idx] = h;
            ik_l[idx] = f2bf(v - bf2f(h));
        }
    } else {
        tsplit_body(invTv, ivT_h, ivT_l, tid);
    }
}

// ---------------- transpose + split fp32 -----------------------------------
__global__ void split_t_kernel(const float* __restrict__ in, u16* __restrict__ hi,
                               u16* __restrict__ lo, int rows, int cols) {
    __shared__ float t[32][33];
    int bx = blockIdx.x, by = blockIdx.y;
    int lx = threadIdx.x & 31, ly = threadIdx.x >> 5;
    for (int r = ly; r < 32; r += 8)
        t[r][lx] = in[(size_t)(by * 32 + r) * cols + bx * 32 + lx];
    __syncthreads();
    for (int r = ly; r < 32; r += 8) {
        float v = t[lx][r];
        size_t o = (size_t)(bx * 32 + r) * rows + by * 32 + lx;
        u16 h = f2bf(v);
        hi[o] = h;
        lo[o] = f2bf(v - bf2f(h));
    }
}

// ---------------- split-bf16 MFMA GEMM (both operands split) ---------------
__global__ __launch_bounds__(256) void gemm_kernel(
    const u16* __restrict__ Ah, const u16* __restrict__ Al, int lda, long aZ, int aDiv,
    const u16* __restrict__ Bh, const u16* __restrict__ Bl, int ldb, long bZ, int bDiv,
    float* __restrict__ C, int ldc, long cZ, int cDiv, int K, float alpha) {
    const int m0 = blockIdx.y * 128, n0 = blockIdx.x * 128;
    const int z = blockIdx.z;
    {
        long ao = (long)(z >> aDiv) * aZ;
        long bo = (long)(z >> bDiv) * bZ;
        Ah += ao; Al += ao; Bh += bo; Bl += bo;
    }
    __shared__ u16 Ash[2][2][128][36];
    __shared__ u16 Bsh[2][2][128][36];

    const int tid = threadIdx.x, lane = tid & 63, wave = tid >> 6;
    const int wr = wave >> 1, wc = wave & 1;
    const int fr = lane & 15, fg8 = (lane >> 4) * 8;
    const int srow = tid >> 2, cc8 = (tid & 3) * 8;

    f32x4 acc[4][4];
#pragma unroll
    for (int m = 0; m < 4; ++m)
#pragma unroll
        for (int n = 0; n < 4; ++n) acc[m][n] = (f32x4)0.0f;

    uint4 rah0, rah1, ral0, ral1, rbh0, rbh1, rbl0, rbl1;
    const size_t aoff0 = (size_t)(m0 + srow) * lda + cc8;
    const size_t aoff1 = aoff0 + (size_t)64 * lda;
    const size_t boff0 = (size_t)(n0 + srow) * ldb + cc8;
    const size_t boff1 = boff0 + (size_t)64 * ldb;

#define G_LOAD(k0) { \
    rah0 = *(const uint4*)(Ah + aoff0 + (k0)); rah1 = *(const uint4*)(Ah + aoff1 + (k0)); \
    ral0 = *(const uint4*)(Al + aoff0 + (k0)); ral1 = *(const uint4*)(Al + aoff1 + (k0)); \
    rbh0 = *(const uint4*)(Bh + boff0 + (k0)); rbh1 = *(const uint4*)(Bh + boff1 + (k0)); \
    rbl0 = *(const uint4*)(Bl + boff0 + (k0)); rbl1 = *(const uint4*)(Bl + boff1 + (k0)); }
#define G_STORE(b) { \
    st8(&Ash[b][0][srow][cc8], rah0); st8(&Ash[b][0][srow + 64][cc8], rah1); \
    st8(&Ash[b][1][srow][cc8], ral0); st8(&Ash[b][1][srow + 64][cc8], ral1); \
    st8(&Bsh[b][0][srow][cc8], rbh0); st8(&Bsh[b][0][srow + 64][cc8], rbh1); \
    st8(&Bsh[b][1][srow][cc8], rbl0); st8(&Bsh[b][1][srow + 64][cc8], rbl1); }

    const int nk = K >> 5;
    G_LOAD(0);
    G_STORE(0);
    __syncthreads();
    int cur = 0;
    for (int ik = 0; ik < nk; ++ik) {
        if (ik + 1 < nk) G_LOAD((ik + 1) << 5);
        bf16x8 bh[4], bl[4];
#pragma unroll
        for (int n = 0; n < 4; ++n) {
            bh[n] = ld16(&Bsh[cur][0][wc * 64 + n * 16 + fr][fg8]);
            bl[n] = ld16(&Bsh[cur][1][wc * 64 + n * 16 + fr][fg8]);
        }
#pragma unroll
        for (int m = 0; m < 4; ++m) {
            bf16x8 ah = ld16(&Ash[cur][0][wr * 64 + m * 16 + fr][fg8]);
            bf16x8 al = ld16(&Ash[cur][1][wr * 64 + m * 16 + fr][fg8]);
#pragma unroll
            for (int n = 0; n < 4; ++n) {
                acc[m][n] = __builtin_amdgcn_mfma_f32_16x16x32_bf16(ah, bh[n], acc[m][n], 0, 0, 0);
                acc[m][n] = __builtin_amdgcn_mfma_f32_16x16x32_bf16(ah, bl[n], acc[m][n], 0, 0, 0);
                acc[m][n] = __builtin_amdgcn_mfma_f32_16x16x32_bf16(al, bh[n], acc[m][n], 0, 0, 0);
            }
        }
        if (ik + 1 < nk) G_STORE(cur ^ 1);
        __syncthreads();
        cur ^= 1;
    }
    const long co = (long)(z >> cDiv) * cZ;
#pragma unroll
    for (int m = 0; m < 4; ++m) {
        int row_b = m0 + wr * 64 + m * 16 + (fg8 >> 1);
#pragma unroll
        for (int n = 0; n < 4; ++n) {
            int col = n0 + wc * 64 + n * 16 + fr;
#pragma unroll
            for (int j = 0; j < 4; ++j)
                C[co + (long)(row_b + j) * ldc + col] = alpha * acc[m][n][j];
        }
    }
#undef G_LOAD
#undef G_STORE
}

// ---------------- merged Q/K head-transform GEMM with fused RoPE -----------
__global__ __launch_bounds__(256) void gemm_qk_kernel(
    const float* __restrict__ QKVf,
    const float* __restrict__ cosp, const float* __restrict__ sinp,
    const u16* __restrict__ iTk_h, const u16* __restrict__ iTk_l,
    const u16* __restrict__ TkT_h, const u16* __restrict__ TkT_l,
    float* __restrict__ q2f, float* __restrict__ k2f) {
    const int m0 = blockIdx.y * 128;
    const int z = blockIdx.z;
    const bool isQ = (z < 16);
    const float* A = QKVf + (isQ ? z * 128 : 2048 + (z - 16) * 128);
    const u16* Bh = isQ ? iTk_h : TkT_h;
    const u16* Bl = isQ ? iTk_l : TkT_l;
    float* C = isQ ? (q2f + z * 128) : (k2f + (z - 16) * 128);
    const int ldc = isQ ? 2048 : 1024;
    const int lda = 4096, ldb = 128, K = 128;

    __shared__ u16 Ash[2][2][128][36];
    __shared__ u16 Bsh[2][2][128][36];
    const int tid = threadIdx.x, lane = tid & 63, wave = tid >> 6;
    const int wr = wave >> 1, wc = wave & 1;
    const int fr = lane & 15, fg8 = (lane >> 4) * 8;
    const int srow = tid >> 2, cc8 = (tid & 3) * 8;

    f32x4 acc[4][4];
#pragma unroll
    for (int m = 0; m < 4; ++m)
#pragma unroll
        for (int n = 0; n < 4; ++n) acc[m][n] = (f32x4)0.0f;

    float4 a00, a01, a10, a11;
    uint4 rbh0, rbh1, rbl0, rbl1;
    const size_t aoff0 = (size_t)(m0 + srow) * lda + cc8;
    const size_t aoff1 = aoff0 + (size_t)64 * lda;
    const size_t boff0 = (size_t)srow * ldb + cc8;
    const size_t boff1 = boff0 + (size_t)64 * ldb;
    const size_t coff0 = (size_t)(m0 + srow) * 128 + cc8;
    const size_t coff1 = coff0 + (size_t)64 * 128;

#define ROPE4(va, vb, vc4, vs4, sg) make_float4( \
    (va).x * (vc4).x + (sg) * (vb).x * (vs4).x, \
    (va).y * (vc4).y + (sg) * (vb).y * (vs4).y, \
    (va).z * (vc4).z + (sg) * (vb).z * (vs4).z, \
    (va).w * (vc4).w + (sg) * (vb).w * (vs4).w)
#define GQ_LOAD(k0) { \
    const int d0_ = (k0) + cc8; \
    const int po_ = (d0_ < 64) ? 64 : -64; \
    const float sg_ = (d0_ < 64) ? -1.0f : 1.0f; \
    float4 ax0 = *(const float4*)(A + aoff0 + (k0)); \
    float4 ax1 = *(const float4*)(A + aoff0 + (k0) + 4); \
    float4 ay0 = *(const float4*)(A + aoff0 + (k0) + po_); \
    float4 ay1 = *(const float4*)(A + aoff0 + (k0) + 4 + po_); \
    float4 pc0 = *(const float4*)(cosp + coff0 + (k0)); \
    float4 pc1 = *(const float4*)(cosp + coff0 + (k0) + 4); \
    float4 ps0 = *(const float4*)(sinp + coff0 + (k0)); \
    float4 ps1 = *(const float4*)(sinp + coff0 + (k0) + 4); \
    a00 = ROPE4(ax0, ay0, pc0, ps0, sg_); a01 = ROPE4(ax1, ay1, pc1, ps1, sg_); \
    float4 bx0 = *(const float4*)(A + aoff1 + (k0)); \
    float4 bx1 = *(const float4*)(A + aoff1 + (k0) + 4); \
    float4 by0 = *(const float4*)(A + aoff1 + (k0) + po_); \
    float4 by1 = *(const float4*)(A + aoff1 + (k0) + 4 + po_); \
    float4 qc0 = *(const float4*)(cosp + coff1 + (k0)); \
    float4 qc1 = *(const float4*)(cosp + coff1 + (k0) + 4); \
    float4 qs0 = *(const float4*)(sinp + coff1 + (k0)); \
    float4 qs1 = *(const float4*)(sinp + coff1 + (k0) + 4); \
    a10 = ROPE4(bx0, by0, qc0, qs0, sg_); a11 = ROPE4(bx1, by1, qc1, qs1, sg_); \
    rbh0 = *(const uint4*)(Bh + boff0 + (k0)); rbh1 = *(const uint4*)(Bh + boff1 + (k0)); \
    rbl0 = *(const uint4*)(Bl + boff0 + (k0)); rbl1 = *(const uint4*)(Bl + boff1 + (k0)); }
#define GQ_STORE(b) { \
    uint4 h0_, l0_, h1_, l1_; \
    cvt8(a00, a01, h0_, l0_); cvt8(a10, a11, h1_, l1_); \
    st8(&Ash[b][0][srow][cc8], h0_); st8(&Ash[b][0][srow + 64][cc8], h1_); \
    st8(&Ash[b][1][srow][cc8], l0_); st8(&Ash[b][1][srow + 64][cc8], l1_); \
    st8(&Bsh[b][0][srow][cc8], rbh0); st8(&Bsh[b][0][srow + 64][cc8], rbh1); \
    st8(&Bsh[b][1][srow][cc8], rbl0); st8(&Bsh[b][1][srow + 64][cc8], rbl1); }

    const int nk = K >> 5;
    GQ_LOAD(0);
    GQ_STORE(0);
    __syncthreads();
    int cur = 0;
    for (int ik = 0; ik < nk; ++ik) {
        if (ik + 1 < nk) GQ_LOAD((ik + 1) << 5);
        bf16x8 bh[4], bl[4];
#pragma unroll
        for (int n = 0; n < 4; ++n) {
            bh[n] = ld16(&Bsh[cur][0][wc * 64 + n * 16 + fr][fg8]);
            bl[n] = ld16(&Bsh[cur][1][wc * 64 + n * 16 + fr][fg8]);
        }
#pragma unroll
        for (int m = 0; m < 4; ++m) {
            bf16x8 ah = ld16(&Ash[cur][0][wr * 64 + m * 16 + fr][fg8]);
            bf16x8 al = ld16(&Ash[cur][1][wr * 64 + m * 16 + fr][fg8]);
#pragma unroll
            for (int n = 0; n < 4; ++n) {
                acc[m][n] = __builtin_amdgcn_mfma_f32_16x16x32_bf16(ah, bh[n], acc[m][n], 0, 0, 0);
                acc[m][n] = __builtin_amdgcn_mfma_f32_16x16x32_bf16(ah, bl[n], acc[m][n], 0, 0, 0);
                acc[m][n] = __builtin_amdgcn_mfma_f32_16x16x32_bf16(al, bh[n], acc[m][n], 0, 0, 0);
            }
        }
        if (ik + 1 < nk) GQ_STORE(cur ^ 1);
        __syncthreads();
        cur ^= 1;
    }
#pragma unroll
    for (int m = 0; m < 4; ++m) {
        int row_b = m0 + wr * 64 + m * 16 + (fg8 >> 1);
#pragma unroll
        for (int n = 0; n < 4; ++n) {
            int col = wc * 64 + n * 16 + fr;
#pragma unroll
            for (int j = 0; j < 4; ++j)
                C[(long)(row_b + j) * ldc + col] = acc[m][n][j];
        }
    }
#undef GQ_LOAD
#undef GQ_STORE
#undef ROPE4
}

// ---------------- o2 GEMM with fused split-K combine on A ------------------
__global__ __launch_bounds__(256) void gemm_o2_kernel(
    const float* __restrict__ o01, const float* __restrict__ ml,
    const u16* __restrict__ Bh, const u16* __restrict__ Bl,
    float* __restrict__ C) {
    const int m0 = blockIdx.y * 128;
    const int z = blockIdx.z;
    const int ldb = 128, K = 128, ldc = 2048;
    __shared__ u16 Ash[2][2][128][36];
    __shared__ u16 Bsh[2][2][128][36];
    const int tid = threadIdx.x, lane = tid & 63, wave = tid >> 6;
    const int wr = wave >> 1, wc = wave & 1;
    const int fr = lane & 15, fg8 = (lane >> 4) * 8;
    const int srow = tid >> 2, cc8 = (tid & 3) * 8;

    f32x4 acc[4][4];
#pragma unroll
    for (int m = 0; m < 4; ++m)
#pragma unroll
        for (int n = 0; n < 4; ++n) acc[m][n] = (f32x4)0.0f;

    const int rs0 = z * 2048 + m0 + srow;
    const int rs1 = rs0 + 64;
    float w0a, w1a, w0b, w1b;
    {
        float ma0 = ml[rs0], la0 = ml[32768 + rs0];
        float ma1 = ml[65536 + rs0], la1 = ml[98304 + rs0];
        float mm = fmaxf(ma0, ma1);
        float e0 = exp2f(ma0 - mm), e1 = exp2f(ma1 - mm);
        float linv = 1.0f / (la0 * e0 + la1 * e1);
        w0a = e0 * linv; w1a = e1 * linv;
        float mb0 = ml[rs1], lb0 = ml[32768 + rs1];
        float mb1 = ml[65536 + rs1], lb1 = ml[98304 + rs1];
        float mmb = fmaxf(mb0, mb1);
        float f0 = exp2f(mb0 - mmb), f1 = exp2f(mb1 - mmb);
        float linvb = 1.0f / (lb0 * f0 + lb1 * f1);
        w0b = f0 * linvb; w1b = f1 * linvb;
    }
    const float* A0 = o01 + (size_t)rs0 * 128 + cc8;
    const float* A1 = o01 + 4194304 + (size_t)rs0 * 128 + cc8;
    const float* B0 = o01 + (size_t)rs1 * 128 + cc8;
    const float* B1 = o01 + 4194304 + (size_t)rs1 * 128 + cc8;

    float4 a00, a01, a10, a11;
    uint4 rbh0, rbh1, rbl0, rbl1;
    const size_t boff0 = (size_t)srow * ldb + cc8;
    const size_t boff1 = boff0 + (size_t)64 * ldb;

#define CMB4(p, q, w0_, w1_) make_float4( \
    (p).x * (w0_) + (q).x * (w1_), (p).y * (w0_) + (q).y * (w1_), \
    (p).z * (w0_) + (q).z * (w1_), (p).w * (w0_) + (q).w * (w1_))
#define GO_LOAD(k0) { \
    float4 p0 = *(const float4*)(A0 + (k0)), p1 = *(const float4*)(A1 + (k0)); \
    float4 p2 = *(const float4*)(A0 + (k0) + 4), p3 = *(const float4*)(A1 + (k0) + 4); \
    a00 = CMB4(p0, p1, w0a, w1a); a01 = CMB4(p2, p3, w0a, w1a); \
    float4 q0 = *(const float4*)(B0 + (k0)), q1 = *(const float4*)(B1 + (k0)); \
    float4 q2 = *(const float4*)(B0 + (k0) + 4), q3 = *(const float4*)(B1 + (k0) + 4); \
    a10 = CMB4(q0, q1, w0b, w1b); a11 = CMB4(q2, q3, w0b, w1b); \
    rbh0 = *(const uint4*)(Bh + boff0 + (k0)); rbh1 = *(const uint4*)(Bh + boff1 + (k0)); \
    rbl0 = *(const uint4*)(Bl + boff0 + (k0)); rbl1 = *(const uint4*)(Bl + boff1 + (k0)); }
#define GO_STORE(b) { \
    uint4 h0_, l0_, h1_, l1_; \
    cvt8(a00, a01, h0_, l0_); cvt8(a10, a11, h1_, l1_); \
    st8(&Ash[b][0][srow][cc8], h0_); st8(&Ash[b][0][srow + 64][cc8], h1_); \
    st8(&Ash[b][1][srow][cc8], l0_); st8(&Ash[b][1][srow + 64][cc8], l1_); \
    st8(&Bsh[b][0][srow][cc8], rbh0); st8(&Bsh[b][0][srow + 64][cc8], rbh1); \
    st8(&Bsh[b][1][srow][cc8], rbl0); st8(&Bsh[b][1][srow + 64][cc8], rbl1); }

    const int nk = K >> 5;
    GO_LOAD(0);
    GO_STORE(0);
    __syncthreads();
    int cur = 0;
    for (int ik = 0; ik < nk; ++ik) {
        if (ik + 1 < nk) GO_LOAD((ik + 1) << 5);
        bf16x8 bh[4], bl[4];
#pragma unroll
        for (int n = 0; n < 4; ++n) {
            bh[n] = ld16(&Bsh[cur][0][wc * 64 + n * 16 + fr][fg8]);
            bl[n] = ld16(&Bsh[cur][1][wc * 64 + n * 16 + fr][fg8]);
        }
#pragma unroll
        for (int m = 0; m < 4; ++m) {
            bf16x8 ah = ld16(&Ash[cur][0][wr * 64 + m * 16 + fr][fg8]);
            bf16x8 al = ld16(&Ash[cur][1][wr * 64 + m * 16 + fr][fg8]);
#pragma unroll
            for (int n = 0; n < 4; ++n) {
                acc[m][n] = __builtin_amdgcn_mfma_f32_16x16x32_bf16(ah, bh[n], acc[m][n], 0, 0, 0);
                acc[m][n] = __builtin_amdgcn_mfma_f32_16x16x32_bf16(ah, bl[n], acc[m][n], 0, 0, 0);
                acc[m][n] = __builtin_amdgcn_mfma_f32_16x16x32_bf16(al, bh[n], acc[m][n], 0, 0, 0);
            }
        }
        if (ik + 1 < nk) GO_STORE(cur ^ 1);
        __syncthreads();
        cur ^= 1;
    }
#pragma unroll
    for (int m = 0; m < 4; ++m) {
        int row_b = m0 + wr * 64 + m * 16 + (fg8 >> 1);
#pragma unroll
        for (int n = 0; n < 4; ++n) {
            int col = wc * 64 + n * 16 + fr;
#pragma unroll
            for (int j = 0; j < 4; ++j)
                C[(long)(row_b + j) * ldc + z * 128 + col] = acc[m][n][j];
        }
    }
#undef GO_LOAD
#undef GO_STORE
#undef CMB4
}

// ---------------- int-bf16 MFMA GEMM (z-batched) ---------------------------
__global__ __launch_bounds__(256) void gemm_int_kernel(
    const u16* __restrict__ A, int lda, const float* __restrict__ sa,
    const u16* __restrict__ B, int ldb, const float* __restrict__ sb,
    float* __restrict__ C, int ldc, long aZ, long bZ, long cZ, int K) {
    const int m0 = blockIdx.y * 128, n0 = blockIdx.x * 128;
    const int z = blockIdx.z;
    A += (long)z * aZ; B += (long)z * bZ; C += (long)z * cZ;
    __shared__ u16 Ash[2][128][36];
    __shared__ u16 Bsh[2][128][36];
    const int tid = threadIdx.x, lane = tid & 63, wave = tid >> 6;
    const int wr = wave >> 1, wc = wave & 1;
    const int fr = lane & 15, fg8 = (lane >> 4) * 8;
    const int srow = tid >> 2, cc8 = (tid & 3) * 8;
    f32x4 acc[4][4];
#pragma unroll
    for (int m = 0; m < 4; ++m)
#pragma unroll
        for (int n = 0; n < 4; ++n) acc[m][n] = (f32x4)0.0f;

    uint4 ra0, ra1, rb0, rb1;
    const size_t aoff0 = (size_t)(m0 + srow) * lda + cc8;
    const size_t aoff1 = aoff0 + (size_t)64 * lda;
    const size_t boff0 = (size_t)(n0 + srow) * ldb + cc8;
    const size_t boff1 = boff0 + (size_t)64 * ldb;
#define GI_LOAD(k0) { \
    ra0 = *(const uint4*)(A + aoff0 + (k0)); ra1 = *(const uint4*)(A + aoff1 + (k0)); \
    rb0 = *(const uint4*)(B + boff0 + (k0)); rb1 = *(const uint4*)(B + boff1 + (k0)); }
#define GI_STORE(b) { \
    st8(&Ash[b][srow][cc8], ra0); st8(&Ash[b][srow + 64][cc8], ra1); \
    st8(&Bsh[b][srow][cc8], rb0); st8(&Bsh[b][srow + 64][cc8], rb1); }
    const int nk = K >> 5;
    GI_LOAD(0);
    GI_STORE(0);
    __syncthreads();
    int cur = 0;
    for (int ik = 0; ik < nk; ++ik) {
        if (ik + 1 < nk) GI_LOAD((ik + 1) << 5);
        bf16x8 bfr[4];
#pragma unroll
        for (int n = 0; n < 4; ++n)
            bfr[n] = ld16(&Bsh[cur][wc * 64 + n * 16 + fr][fg8]);
#pragma unroll
        for (int m = 0; m < 4; ++m) {
            bf16x8 ah = ld16(&Ash[cur][wr * 64 + m * 16 + fr][fg8]);
#pragma unroll
            for (int n = 0; n < 4; ++n)
                acc[m][n] = __builtin_amdgcn_mfma_f32_16x16x32_bf16(ah, bfr[n], acc[m][n], 0, 0, 0);
        }
        if (ik + 1 < nk) GI_STORE(cur ^ 1);
        __syncthreads();
        cur ^= 1;
    }
#pragma unroll
    for (int m = 0; m < 4; ++m) {
        int row_b = m0 + wr * 64 + m * 16 + (fg8 >> 1);
#pragma unroll
        for (int n = 0; n < 4; ++n) {
            int col = n0 + wc * 64 + n * 16 + fr;
            float sc = sb[col];
#pragma unroll
            for (int j = 0; j < 4; ++j)
                C[(long)(row_b + j) * ldc + col] = acc[m][n][j] * sa[row_b + j] * sc;
        }
    }
#undef GI_LOAD
#undef GI_STORE
}

// ---------------- per-row fake_quant (wide rows) ---------------------------
__global__ void rowquant_int_kernel(const float* __restrict__ x, u16* __restrict__ qi,
                                    float* __restrict__ sc, int cols) {
    __shared__ float red[256];
    int row = blockIdx.x, tid = threadIdx.x;
    const float* p = x + (size_t)row * cols;
    u16* q = qi + (size_t)row * cols;
    float m = 0.0f;
    for (int j = tid; j < cols; j += 256) m = fmaxf(m, fabsf(p[j]));
    red[tid] = m; __syncthreads();
    for (int s = 128; s > 0; s >>= 1) {
        if (tid < s) red[tid] = fmaxf(red[tid], red[tid + s]);
        __syncthreads();
    }
    float scale = fmaxf(red[0] / 127.0f, 1e-8f);
    if (tid == 0) sc[row] = scale;
    for (int j = tid; j < cols; j += 256) {
        float v = rintf(p[j] / scale);
        v = fminf(fmaxf(v, -127.0f), 127.0f);
        q[j] = f2bf(v);
    }
}

// ---------------- dual per-row fake_quant (two tensors, one launch) --------
__global__ void rowquant2_kernel(const float* __restrict__ x0, u16* __restrict__ q0,
                                 float* __restrict__ s0,
                                 const float* __restrict__ x1, u16* __restrict__ q1,
                                 float* __restrict__ s1) {
    __shared__ float red[256];
    int bid = blockIdx.x, tid = threadIdx.x;
    const float* p; u16* q; float* sc; int row;
    if (bid < 2048) { p = x0; q = q0; sc = s0; row = bid; }
    else            { p = x1; q = q1; sc = s1; row = bid - 2048; }
    p += (size_t)row * 2048;
    q += (size_t)row * 2048;
    float m = 0.0f;
    for (int j = tid; j < 2048; j += 256) m = fmaxf(m, fabsf(p[j]));
    red[tid] = m; __syncthreads();
    for (int s = 128; s > 0; s >>= 1) {
        if (tid < s) red[tid] = fmaxf(red[tid], red[tid + s]);
        __syncthreads();
    }
    float scale = fmaxf(red[0] / 127.0f, 1e-8f);
    if (tid == 0) sc[row] = scale;
    for (int j = tid; j < 2048; j += 256) {
        float v = rintf(p[j] / scale);
        v = fminf(fmaxf(v, -127.0f), 127.0f);
        q[j] = f2bf(v);
    }
}

// ---------------- per-row fake_quant, 128-col rows, 1 wave/row -------------
__global__ void rowquant_w_kernel(const float* __restrict__ x, u16* __restrict__ qi,
                                  float* __restrict__ sc) {
    int row = blockIdx.x * 4 + (threadIdx.x >> 6);
    int lane = threadIdx.x & 63;
    const float* p = x + (size_t)row * 128;
    float2 v = *(const float2*)(p + lane * 2);
    float m = fmaxf(fabsf(v.x), fabsf(v.y));
#pragma unroll
    for (int off = 1; off < 64; off <<= 1) m = fmaxf(m, __shfl_xor(m, off));
    float scale = fmaxf(m / 127.0f, 1e-8f);
    if (lane == 0) sc[row] = scale;
    float a = rintf(v.x / scale), b = rintf(v.y / scale);
    a = fminf(fmaxf(a, -127.0f), 127.0f);
    b = fminf(fmaxf(b, -127.0f), 127.0f);
    unsigned pk = f2bf(a) | ((unsigned)f2bf(b) << 16);
    *(unsigned*)(qi + (size_t)row * 128 + lane * 2) = pk;
}

// ---------------- fused V fake_quant + transpose ---------------------------
__global__ __launch_bounds__(256) void quantT_v_kernel(
    const float* __restrict__ QKVf, u16* __restrict__ vTi, float* __restrict__ vs) {
    __shared__ u16 tile[128][72];
    const int st = blockIdx.x, g = blockIdx.y;
    const int t = threadIdx.x;
    const int sl = t >> 2, dc = (t & 3) * 32;
    const int s = st * 64 + sl;
    const float* p = QKVf + (size_t)s * 4096 + 3072 + g * 128 + dc;
    float4 vr[8];
    float m = 0.0f;
#pragma unroll
    for (int q = 0; q < 8; ++q) {
        vr[q] = *(const float4*)(p + q * 4);
        m = fmaxf(m, fmaxf(fmaxf(fabsf(vr[q].x), fabsf(vr[q].y)),
                           fmaxf(fabsf(vr[q].z), fabsf(vr[q].w))));
    }
    m = fmaxf(m, __shfl_xor(m, 1));
    m = fmaxf(m, __shfl_xor(m, 2));
    float scale = fmaxf(m / 127.0f, 1e-8f);
    if ((t & 3) == 0) vs[s * 8 + g] = scale;
#pragma unroll
    for (int q = 0; q < 8; ++q) {
        float vv[4] = {vr[q].x, vr[q].y, vr[q].z, vr[q].w};
#pragma unroll
        for (int e = 0; e < 4; ++e) {
            float qv = rintf(vv[e] / scale);
            qv = fminf(fmaxf(qv, -127.0f), 127.0f);
            tile[dc + q * 4 + e][sl] = f2bf(qv);
        }
    }
    __syncthreads();
    const int d = t >> 1, sc0 = (t & 1) * 32;
    u16* dst = vTi + (size_t)(g * 128 + d) * 2048 + st * 64 + sc0;
#pragma unroll
    for (int q = 0; q < 4; ++q) {
        u16 tmp[8];
#pragma unroll
        for (int e = 0; e < 8; ++e) tmp[e] = tile[d][sc0 + q * 8 + e];
        uint4 v;
        v.x = tmp[0] | ((unsigned)tmp[1] << 16); v.y = tmp[2] | ((unsigned)tmp[3] << 16);
        v.z = tmp[4] | ((unsigned)tmp[5] << 16); v.w = tmp[6] | ((unsigned)tmp[7] << 16);
        *(uint4*)(dst + q * 8) = v;
    }
}

// ---------------- elementwise add ------------------------------------------
__global__ void add2_kernel(const float* __restrict__ a, const float* __restrict__ b,
                            float* __restrict__ o) {
    int i = (blockIdx.x * 256 + threadIdx.x) * 4;
    float4 x = *(const float4*)(a + i);
    float4 y = *(const float4*)(b + i);
    x.x += y.x; x.y += y.y; x.z += y.z; x.w += y.w;
    *(float4*)(o + i) = x;
}

// ---------------- flash attention v5 (unchanged) ---------------------------
__global__ __launch_bounds__(256, 2) void flash_kernel(
    const float* __restrict__ q2f,
    const u16* __restrict__ k2i, const float* __restrict__ ksc,
    const u16* __restrict__ vTi, const float* __restrict__ vsc,
    float* __restrict__ obuf, float* __restrict__ mlbuf) {
    const int h = blockIdx.x, part = blockIdx.y, qt = 31 - blockIdx.z, g = h >> 1;
    __shared__ u16 Ksh[2][64 * 128];
    __shared__ u16 Vsh[2][128 * 64];
    __shared__ u16 Psh[4][16 * 64];
    __shared__ float Kss[2][64];
    __shared__ float Vss[2][64];

    const int tid = threadIdx.x, lane = tid & 63, w = tid >> 6;
    const int lc = lane & 15, lg = lane >> 4;
    const float scale = 0.08838834764831845f;
    const float LOG2E = 1.4426950408889634f;
    const float THR = 10.0f;

    bf16x8 qh[4], ql[4];
    {
        int s = qt * 64 + w * 16 + lc;
        const float* qp = q2f + (size_t)s * 2048 + h * 128 + lg * 8;
#pragma unroll
        for (int kk = 0; kk < 4; ++kk) {
            float4 v0 = *(const float4*)(qp + kk * 32);
            float4 v1 = *(const float4*)(qp + kk * 32 + 4);
            float vv[8] = {v0.x, v0.y, v0.z, v0.w, v1.x, v1.y, v1.z, v1.w};
#pragma unroll
            for (int e = 0; e < 8; ++e) {
                float x = vv[e] * scale;
                u16 hh = f2bf(x);
                qh[kk][e] = (short)hh;
                ql[kk][e] = (short)f2bf(x - bf2f(hh));
            }
        }
    }

    f32x4 acc_o[8];
#pragma unroll
    for (int nn = 0; nn < 8; ++nn) acc_o[nn] = (f32x4)0.0f;
    float mj = -1e30f, lj = 0.0f;

    const int p0cnt = (qt + 2) >> 1;
    const int tn = (part == 0) ? p0cnt : (qt + 1 - p0cnt);
    const int t0 = (part == 0) ? 0 : p0cnt;

    const int kr = tid >> 2, kc = tid & 3;
    const int vd = tid >> 1, vc0 = (tid & 1) * 4;
    uint4 kg0, kg1, kg2, kg3, vg0, vg1, vg2, vg3;
    float sreg = 0.0f;

#define STAGE_LOAD(tg) { \
    const int j0_ = (tg) * 64; \
    const u16* kp_ = k2i + (size_t)(j0_ + kr) * 1024 + g * 128; \
    kg0 = *(const uint4*)(kp_ + kc * 8); \
    kg1 = *(const uint4*)(kp_ + (kc + 4) * 8); \
    kg2 = *(const uint4*)(kp_ + (kc + 8) * 8); \
    kg3 = *(const uint4*)(kp_ + (kc + 12) * 8); \
    const u16* vp_ = vTi + (size_t)(g * 128 + vd) * 2048 + j0_; \
    vg0 = *(const uint4*)(vp_ + vc0 * 8); \
    vg1 = *(const uint4*)(vp_ + (vc0 + 1) * 8); \
    vg2 = *(const uint4*)(vp_ + (vc0 + 2) * 8); \
    vg3 = *(const uint4*)(vp_ + (vc0 + 3) * 8); \
    if (tid < 64) sreg = ksc[(j0_ + tid) * 8 + g] * LOG2E; \
    else if (tid < 128) sreg = vsc[(j0_ + tid - 64) * 8 + g]; }

#define STAGE_WRITE(b) { \
    *(uint4*)(&Ksh[b][kr * 128 + ((kc ^ (kr & 7)) << 3)]) = kg0; \
    *(uint4*)(&Ksh[b][kr * 128 + (((kc + 4) ^ (kr & 7)) << 3)]) = kg1; \
    *(uint4*)(&Ksh[b][kr * 128 + (((kc + 8) ^ (kr & 7)) << 3)]) = kg2; \
    *(uint4*)(&Ksh[b][kr * 128 + (((kc + 12) ^ (kr & 7)) << 3)]) = kg3; \
    *(uint4*)(&Vsh[b][vd * 64 + ((vc0 ^ (vd & 7)) << 3)]) = vg0; \
    *(uint4*)(&Vsh[b][vd * 64 + (((vc0 + 1) ^ (vd & 7)) << 3)]) = vg1; \
    *(uint4*)(&Vsh[b][vd * 64 + (((vc0 + 2) ^ (vd & 7)) << 3)]) = vg2; \
    *(uint4*)(&Vsh[b][vd * 64 + (((vc0 + 3) ^ (vd & 7)) << 3)]) = vg3; \
    if (tid < 64) Kss[b][tid] = sreg; \
    else if (tid < 128) Vss[b][tid - 64] = sreg; }

    if (tn > 0) {
        STAGE_LOAD(t0);
        STAGE_WRITE(0);
    }
    __syncthreads();
    for (int t = 0; t < tn; ++t) {
        const int cur = t & 1;
        const int tg = t0 + t;
        if (t + 1 < tn) STAGE_LOAD(t0 + t + 1);

        f32x4 accs[4];
#pragma unroll
        for (int n = 0; n < 4; ++n) accs[n] = (f32x4)0.0f;
#pragma unroll
        for (int n = 0; n < 4; ++n) {
#pragma unroll
            for (int kk = 0; kk < 4; ++kk) {
                bf16x8 kf = ld16(&Ksh[cur][(n * 16 + lc) * 128 + (((kk * 4 + lg) ^ (lc & 7)) << 3)]);
                accs[n] = __builtin_amdgcn_mfma_f32_16x16x32_bf16(kf, qh[kk], accs[n], 0, 0, 0);
                accs[n] = __builtin_amdgcn_mfma_f32_16x16x32_bf16(kf, ql[kk], accs[n], 0, 0, 0);
            }
        }
#pragma unroll
        for (int n = 0; n < 4; ++n)
#pragma unroll
            for (int j = 0; j < 4; ++j)
                accs[n][j] *= Kss[cur][n * 16 + lg * 4 + j];
        if (tg == qt) {
            int qg = qt * 64 + w * 16 + lc;
#pragma unroll
            for (int n = 0; n < 4; ++n)
#pragma unroll
                for (int j = 0; j < 4; ++j) {
                    int kgl = tg * 64 + n * 16 + lg * 4 + j;
                    if (kgl > qg) accs[n][j] = -3.0e38f;
                }
        }

        float pm = accs[0][0];
#pragma unroll
        for (int n = 0; n < 4; ++n)
#pragma unroll
            for (int j = 0; j < 4; ++j) pm = fmaxf(pm, accs[n][j]);
        pm = fmaxf(pm, __shfl_xor(pm, 16));
        pm = fmaxf(pm, __shfl_xor(pm, 32));
        bool need = pm > mj + THR;
        float mn = need ? pm : mj;
        float sf = need ? exp2f(mj - mn) : 1.0f;
        mj = mn;
        if (__any(need)) {
            float sfj[4];
#pragma unroll
            for (int j = 0; j < 4; ++j) sfj[j] = __shfl(sf, lg * 4 + j);
#pragma unroll
            for (int nn = 0; nn < 8; ++nn)
#pragma unroll
                for (int j = 0; j < 4; ++j) acc_o[nn][j] *= sfj[j];
        }
        float rowsum = 0.0f;
#pragma unroll
        for (int n = 0; n < 4; ++n)
#pragma unroll
            for (int j = 0; j < 4; ++j) {
                float p = exp2f(accs[n][j] - mj);
                accs[n][j] = p;
                rowsum += p;
            }
        rowsum += __shfl_xor(rowsum, 16);
        rowsum += __shfl_xor(rowsum, 32);
        lj = lj * sf + rowsum;

#pragma unroll
        for (int n = 0; n < 4; ++n)
#pragma unroll
            for (int jp = 0; jp < 2; ++jp) {
                int k = n * 16 + lg * 4 + jp * 2;
                unsigned val = f2bf(accs[n][jp * 2] * Vss[cur][k]) |
                               ((unsigned)f2bf(accs[n][jp * 2 + 1] * Vss[cur][k + 1]) << 16);
                int cch = k >> 3;
                *(unsigned*)(&Psh[w][lc * 64 + ((cch ^ (lc & 7)) << 3) + (k & 7)]) = val;
            }
        bf16x8 pf[2];
#pragma unroll
        for (int kk = 0; kk < 2; ++kk)
            pf[kk] = ld16(&Psh[w][lc * 64 + (((kk * 4 + lg) ^ (lc & 7)) << 3)]);

#pragma unroll
        for (int nn = 0; nn < 8; ++nn) {
            int d = nn * 16 + lc;
#pragma unroll
            for (int kk = 0; kk < 2; ++kk) {
                bf16x8 vf = ld16(&Vsh[cur][d * 64 + (((kk * 4 + lg) ^ (d & 7)) << 3)]);
                acc_o[nn] = __builtin_amdgcn_mfma_f32_16x16x32_bf16(pf[kk], vf, acc_o[nn], 0, 0, 0);
            }
        }
        if (t + 1 < tn) STAGE_WRITE(cur ^ 1);
        __syncthreads();
    }
#undef STAGE_LOAD
#undef STAGE_WRITE

    float* op = obuf + (size_t)part * 4194304 + ((size_t)h * 2048 + qt * 64 + w * 16) * 128;
#pragma unroll
    for (int nn = 0; nn < 8; ++nn)
#pragma unroll
        for (int j = 0; j < 4; ++j)
            op[(lg * 4 + j) * 128 + nn * 16 + lc] = acc_o[nn][j];
    if (lg == 0) {
        int rs = h * 2048 + qt * 64 + w * 16 + lc;
        mlbuf[part * 65536 + rs] = mj;
        mlbuf[part * 65536 + 32768 + rs] = lj;
    }
}

// ===========================================================================
extern "C" void kernel_launch(void* const* d_in, const int* in_sizes, int n_in,
                              void* d_out, int out_size, void* d_ws, size_t ws_size,
                              hipStream_t stream) {
    const float* hidden = (const float*)d_in[0];
    const float* cosp   = (const float*)d_in[1];
    const float* sinp   = (const float*)d_in[2];
    const float* Wq     = (const float*)d_in[3];
    const float* Wk     = (const float*)d_in[4];
    const float* Wv     = (const float*)d_in[5];
    const float* Wo     = (const float*)d_in[6];
    const float* Lp     = (const float*)d_in[7];
    const float* Rp     = (const float*)d_in[8];
    const float* diag   = (const float*)d_in[9];
    const float* Tkp    = (const float*)d_in[10];
    const float* Tvp    = (const float*)d_in[11];
    float* out = (float*)d_out;

    const size_t MiB = 1ull << 20;
    char* W = (char*)d_ws;
    auto F = [&](size_t mb) { return (float*)(W + mb * MiB); };
    auto U = [&](size_t mb) { return (u16*)(W + mb * MiB); };
    const long HP2 = 2097152;

    float* dsc   = (float*)d_out;
    float* invL  = dsc;
    float* invR  = dsc + 1024;
    float* invTk = dsc + 5120;
    float* invTv = dsc + 21504;
    u16* sm = (u16*)(dsc + 37888);
    u16* invTk_sh = sm;              u16* invTk_sl = sm + 16384;
    u16* TkT_sh   = sm + 2 * 16384;  u16* TkT_sl   = sm + 3 * 16384;
    u16* invTvT_sh= sm + 4 * 16384;  u16* invTvT_sl= sm + 5 * 16384;
    u16* TvT_sh   = sm + 6 * 16384;  u16* TvT_sl   = sm + 7 * 16384;

    float* xs    = F(88);
    float* wqkvs = xs + 2048;
    float* wqs   = wqkvs;
    float* wks   = wqkvs + 2048;
    float* wvs   = wqkvs + 3072;
    float* k2s   = wqkvs + 4096;
    float* vs    = k2s + 16384;
    float* o2s   = vs + 16384;
    float* wos   = o2s + 2048;

    // ---- P0a: gj(L,R) + kron(hidden) + Tk/Tv transpose-splits ----
    u16* Xi = U(0);
    p0a_kernel<<<516, 1024, 0, stream>>>(Lp, invL, Rp, invR, hidden, diag, Xi, xs,
                                         Tkp, TkT_sh, TkT_sl, Tvp, TvT_sh, TvT_sl);

    // ---- P0b: gj(Tk,Tv) + weight krons (need only invL/invR) ----
    u16* WQKVi = U(8);
    u16* WVi   = U(20);
    float* WvP = F(24);
    p0b_kernel<<<1026, 1024, 0, stream>>>(Tkp, invTk, Tvp, invTv, Wq, Wk, Wv, diag,
                                          invL, invR, WQKVi, wqs, U(16), wks, WvP);

    // ---- ps: split(invTk) + transpose-split(invTv) ----
    ps_kernel<<<2, 1024, 0, stream>>>(invTk, invTk_sh, invTk_sl,
                                      invTv, invTvT_sh, invTvT_sl);

    // ---- Wv_eff: Tv^T per kv-head, then quant ----
    u16* WVPt_s = U(32);
    split_t_kernel<<<dim3(64, 32), 256, 0, stream>>>(WvP, WVPt_s, WVPt_s + HP2, 1024, 2048);
    float* WVf = F(72);
    gemm_kernel<<<dim3(16, 1, 8), 256, 0, stream>>>(
        TvT_sh, TvT_sl, 128, 0, 0, WVPt_s, WVPt_s + HP2, 1024, 128, 0,
        WVf, 2048, (long)128 * 2048, 0, 128, 1.0f);
    rowquant_int_kernel<<<1024, 256, 0, stream>>>(WVf, WVi, wvs, 2048);

    // ---- P2: merged QKV projection GEMM ----
    float* QKVf = F(40);
    gemm_int_kernel<<<dim3(32, 16), 256, 0, stream>>>(Xi, 2048, xs, WQKVi, 2048, wqkvs,
                                                      QKVf, 4096, 0, 0, 0, 2048);

    // merged Q+K head transforms with fused RoPE (one launch, 384 blocks)
    float* q2f = F(72);
    float* k2f = F(32);
    gemm_qk_kernel<<<dim3(1, 16, 24), 256, 0, stream>>>(
        QKVf, cosp, sinp, invTk_sh, invTk_sl, TkT_sh, TkT_sl, q2f, k2f);
    u16* k2i = U(8);
    rowquant_w_kernel<<<4096, 256, 0, stream>>>(k2f, k2i, k2s);

    // V path
    u16* vTi = U(16);
    quantT_v_kernel<<<dim3(32, 8), 256, 0, stream>>>(QKVf, vTi, vs);

    // ---- P3: flash attention ----
    float* o01 = F(40);
    float* ml  = F(32);
    flash_kernel<<<dim3(16, 2, 32), 256, 0, stream>>>(q2f, k2i, k2s, vTi, vs, o01, ml);

    // ---- P4: o2 = combine(o01) @ inv(Tv) fused; quant; final GEMM ----
    float* o2f = F(16);
    gemm_o2_kernel<<<dim3(1, 16, 16), 256, 0, stream>>>(
        o01, ml, invTvT_sh, invTvT_sl, o2f);
    u16* o2i = U(32);
    u16* Woi = U(40);
    rowquant2_kernel<<<4096, 256, 0, stream>>>(o2f, o2i, o2s, Wo, Woi, wos);
    float* C0 = F(48);
    gemm_int_kernel<<<dim3(16, 16, 2), 256, 0, stream>>>(o2i, 2048, o2s, Woi, 2048, wos,
                                                         C0, 2048, 1024, 1024, 4194304, 1024);
    add2_kernel<<<4096, 256, 0, stream>>>(C0, C0 + 4194304, out);

    (void)in_sizes; (void)n_in; (void)out_size; (void)ws_size;
}

// Round 26
// 445.486 us; speedup vs baseline: 1.0801x; 1.0801x over previous
//
#include <hip/hip_runtime.h>
#include <math.h>

typedef unsigned short u16;
typedef __attribute__((ext_vector_type(8))) short bf16x8;
typedef __attribute__((ext_vector_type(4))) float f32x4;

__device__ __forceinline__ u16 f2bf(float x) {
    union { float f; unsigned int u; } c; c.f = x;
    unsigned int r = c.u + 0x7fffu + ((c.u >> 16) & 1u);
    return (u16)(r >> 16);
}
__device__ __forceinline__ float bf2f(u16 h) {
    union { unsigned int u; float f; } c; c.u = ((unsigned int)h) << 16;
    return c.f;
}
__device__ __forceinline__ bf16x8 ld16(const u16* p) {
    bf16x8 r;
    ((uint2*)&r)[0] = *(const uint2*)p;
    ((uint2*)&r)[1] = *(const uint2*)(p + 4);
    return r;
}
__device__ __forceinline__ void st8(u16* dst, uint4 r) {
    *(uint2*)dst = make_uint2(r.x, r.y);
    *(uint2*)(dst + 4) = make_uint2(r.z, r.w);
}
__device__ __forceinline__ void cvt8(const float4& v0, const float4& v1,
                                     uint4& hi, uint4& lo) {
    float vv[8] = {v0.x, v0.y, v0.z, v0.w, v1.x, v1.y, v1.z, v1.w};
    u16 h[8], l[8];
#pragma unroll
    for (int e = 0; e < 8; ++e) {
        h[e] = f2bf(vv[e]);
        l[e] = f2bf(vv[e] - bf2f(h[e]));
    }
    hi.x = h[0] | ((unsigned)h[1] << 16); hi.y = h[2] | ((unsigned)h[3] << 16);
    hi.z = h[4] | ((unsigned)h[5] << 16); hi.w = h[6] | ((unsigned)h[7] << 16);
    lo.x = l[0] | ((unsigned)l[1] << 16); lo.y = l[2] | ((unsigned)l[3] << 16);
    lo.z = l[4] | ((unsigned)l[5] << 16); lo.w = l[6] | ((unsigned)l[7] << 16);
}

// ---------------- P0 fused: gj4 (blocks 0-3) + kron(hidden) (blocks 4+) ----
__global__ __launch_bounds__(1024) void p0_kernel(
    const float* __restrict__ A0, float* __restrict__ I0,
    const float* __restrict__ A1, float* __restrict__ I1,
    const float* __restrict__ A2, float* __restrict__ I2,
    const float* __restrict__ A3, float* __restrict__ I3,
    const float* __restrict__ X, const float* __restrict__ dg,
    const float* __restrict__ Lk, const float* __restrict__ Rk,
    u16* __restrict__ Yq, float* __restrict__ Ysc) {
    const int tid = threadIdx.x;
    if (blockIdx.x < 4) {
        __shared__ float rowbuf[2][128];
        const float* A; float* out; int N;
        switch (blockIdx.x) {
            case 0:  A = A0; out = I0; N = 32;  break;
            case 1:  A = A1; out = I1; N = 64;  break;
            case 2:  A = A2; out = I2; N = 128; break;
            default: A = A3; out = I3; N = 128; break;
        }
        const int i = tid >> 3, g = tid & 7, c0 = g * 16;
        const int rl = (i & 7) << 3;
        float r[16];
#pragma unroll
        for (int e = 0; e < 16; ++e) {
            int j = c0 + e;
            r[e] = (i < N && j < N) ? A[i * N + j] : ((i == j) ? 1.0f : 0.0f);
        }
        if (i == 0) {
            float ip = 1.0f / __shfl(r[0], rl, 64);
#pragma unroll
            for (int e = 0; e < 16; ++e)
                rowbuf[0][c0 + e] = (c0 + e == 0) ? ip : r[e] * ip;
        }
        __syncthreads();
        const int ng = N >> 4;
        for (int k16 = 0; k16 < ng; ++k16) {
#pragma unroll
            for (int e = 0; e < 16; ++e) {
                const int k = (k16 << 4) + e;
                const int pb = k & 1;
                float ci = __shfl(r[e], rl + k16, 64);
                float4 rb0 = *(const float4*)&rowbuf[pb][c0];
                float4 rb1 = *(const float4*)&rowbuf[pb][c0 + 4];
                float4 rb2 = *(const float4*)&rowbuf[pb][c0 + 8];
                float4 rb3 = *(const float4*)&rowbuf[pb][c0 + 12];
                float rb[16] = {rb0.x, rb0.y, rb0.z, rb0.w, rb1.x, rb1.y, rb1.z, rb1.w,
                                rb2.x, rb2.y, rb2.z, rb2.w, rb3.x, rb3.y, rb3.z, rb3.w};
                if (i == k) {
#pragma unroll
                    for (int e2 = 0; e2 < 16; ++e2) r[e2] = rb[e2];
                } else {
#pragma unroll
                    for (int e2 = 0; e2 < 16; ++e2) {
                        float v = (c0 + e2 == k) ? 0.0f : r[e2];
                        r[e2] = fmaf(-ci, rb[e2], v);
                    }
                }
                if (k + 1 < N && i == k + 1) {
                    const int en = (e + 1) & 15;
                    const int gn = (e == 15) ? k16 + 1 : k16;
                    float ip = 1.0f / __shfl(r[en], rl + gn, 64);
#pragma unroll
                    for (int e2 = 0; e2 < 16; ++e2)
                        rowbuf[pb ^ 1][c0 + e2] = (c0 + e2 == k + 1) ? ip : r[e2] * ip;
                }
                __syncthreads();
            }
        }
        if (i < N)
#pragma unroll
            for (int e = 0; e < 16; ++e) {
                int j = c0 + e;
                if (j < N) out[i * N + j] = r[e];
            }
    } else {
        // ---- kron(hidden): 4 rows/block, kron-256 arithmetic per group ----
        __shared__ float Al[32 * 33];
        __shared__ float Bl[64 * 65];
        __shared__ float Tl[4][32 * 65];
        __shared__ float red[1024];
        {
            int c = tid >> 5, a = tid & 31;
            Al[c * 33 + a] = Lk[c * 32 + a];
        }
        for (int idx = tid; idx < 4096; idx += 1024) {
            int d = idx >> 6, b = idx & 63;
            Bl[d * 65 + b] = Rk[d * 64 + b];
        }
        __syncthreads();

        const int g = tid >> 8, t = tid & 255;
        const int row = (blockIdx.x - 4) * 4 + g;
        const int c = t >> 3, b0 = (t & 7) * 8;

        const float* xp = X + (size_t)row * 2048 + c * 64;
        const float* dgp = dg + c * 64;
        float tacc[8];
#pragma unroll
        for (int jj = 0; jj < 8; ++jj) tacc[jj] = 0.0f;
        for (int d0 = 0; d0 < 64; d0 += 4) {
            float4 xv4 = *(const float4*)(xp + d0);
            float4 dg4 = *(const float4*)(dgp + d0);
            float xs4[4] = {xv4.x * dg4.x, xv4.y * dg4.y, xv4.z * dg4.z, xv4.w * dg4.w};
#pragma unroll
            for (int e = 0; e < 4; ++e) {
                float xv = xs4[e];
#pragma unroll
                for (int jj = 0; jj < 8; ++jj)
                    tacc[jj] = fmaf(xv, Bl[(d0 + e) * 65 + b0 + jj], tacc[jj]);
            }
        }
#pragma unroll
        for (int jj = 0; jj < 8; ++jj) Tl[g][c * 65 + b0 + jj] = tacc[jj];
        __syncthreads();

        const int a = t >> 3;
        float y[8];
#pragma unroll
        for (int jj = 0; jj < 8; ++jj) y[jj] = 0.0f;
        for (int c2 = 0; c2 < 32; ++c2) {
            float av = Al[c2 * 33 + a];
#pragma unroll
            for (int jj = 0; jj < 8; ++jj)
                y[jj] = fmaf(av, Tl[g][c2 * 65 + b0 + jj], y[jj]);
        }

        float am = 0.0f;
#pragma unroll
        for (int jj = 0; jj < 8; ++jj) am = fmaxf(am, fabsf(y[jj]));
        red[tid] = am;
        __syncthreads();
        for (int s = 128; s > 0; s >>= 1) {
            if (t < s) red[tid] = fmaxf(red[tid], red[tid + s]);
            __syncthreads();
        }
        float scale = fmaxf(red[g << 8] / 127.0f, 1e-8f);
        if (t == 0) Ysc[row] = scale;
        u16 qq[8];
#pragma unroll
        for (int e = 0; e < 8; ++e) {
            float v = rintf(y[e] / scale);
            v = fminf(fmaxf(v, -127.0f), 127.0f);
            qq[e] = f2bf(v);
        }
        uint4 pk;
        pk.x = qq[0] | ((unsigned)qq[1] << 16); pk.y = qq[2] | ((unsigned)qq[3] << 16);
        pk.z = qq[4] | ((unsigned)qq[5] << 16); pk.w = qq[6] | ((unsigned)qq[7] << 16);
        *(uint4*)(Yq + (size_t)row * 2048 + t * 8) = pk;
    }
}

// ---------------- fused kron transform (256 thr, ILP-8) --------------------
template <int TA, int TB, int OUTQ, int DIV>
__global__ __launch_bounds__(256) void kron_kernel(
    const float* __restrict__ X, const float* __restrict__ scIn,
    const float* __restrict__ A, const float* __restrict__ B,
    u16* __restrict__ Yq, float* __restrict__ Ysc, float* __restrict__ Yf) {
    __shared__ float Al[32 * 33];
    __shared__ float Bl[64 * 65];
    __shared__ float Xl[32 * 65];
    __shared__ float Tl[32 * 65];
    __shared__ float red[256];
    const int tid = threadIdx.x;
    for (int idx = tid; idx < 1024; idx += 256) {
        int c = idx >> 5, a = idx & 31;
        Al[c * 33 + a] = TA ? A[a * 32 + c] : A[c * 32 + a];
    }
    for (int idx = tid; idx < 4096; idx += 256) {
        int d = idx >> 6, b = idx & 63;
        Bl[d * 65 + b] = TB ? B[b * 64 + d] : B[d * 64 + b];
    }
    const int row = blockIdx.x;
    const float* xp = X + (size_t)row * 2048;
    for (int j = tid; j < 2048; j += 256) {
        float sc = DIV ? (1.0f / scIn[j]) : scIn[j];
        Xl[(j >> 6) * 65 + (j & 63)] = xp[j] * sc;
    }
    __syncthreads();

    const int c = tid >> 3, b0 = (tid & 7) * 8;
    float t[8];
#pragma unroll
    for (int jj = 0; jj < 8; ++jj) t[jj] = 0.0f;
    for (int d = 0; d < 64; ++d) {
        float xv = Xl[c * 65 + d];
#pragma unroll
        for (int jj = 0; jj < 8; ++jj)
            t[jj] = fmaf(xv, Bl[d * 65 + b0 + jj], t[jj]);
    }
#pragma unroll
    for (int jj = 0; jj < 8; ++jj) Tl[c * 65 + b0 + jj] = t[jj];
    __syncthreads();

    const int a = tid >> 3;
    float y[8];
#pragma unroll
    for (int jj = 0; jj < 8; ++jj) y[jj] = 0.0f;
    for (int c2 = 0; c2 < 32; ++c2) {
        float av = Al[c2 * 33 + a];
#pragma unroll
        for (int jj = 0; jj < 8; ++jj)
            y[jj] = fmaf(av, Tl[c2 * 65 + b0 + jj], y[jj]);
    }

    if (OUTQ) {
        float am = 0.0f;
#pragma unroll
        for (int jj = 0; jj < 8; ++jj) am = fmaxf(am, fabsf(y[jj]));
        red[tid] = am;
        __syncthreads();
        for (int s = 128; s > 0; s >>= 1) {
            if (tid < s) red[tid] = fmaxf(red[tid], red[tid + s]);
            __syncthreads();
        }
        float scale = fmaxf(red[0] / 127.0f, 1e-8f);
        if (tid == 0) Ysc[row] = scale;
        u16 qq[8];
#pragma unroll
        for (int e = 0; e < 8; ++e) {
            float v = rintf(y[e] / scale);
            v = fminf(fmaxf(v, -127.0f), 127.0f);
            qq[e] = f2bf(v);
        }
        uint4 pk;
        pk.x = qq[0] | ((unsigned)qq[1] << 16); pk.y = qq[2] | ((unsigned)qq[3] << 16);
        pk.z = qq[4] | ((unsigned)qq[5] << 16); pk.w = qq[6] | ((unsigned)qq[7] << 16);
        *(uint4*)(Yq + (size_t)row * 2048 + tid * 8) = pk;
    } else {
        float* yp = Yf + (size_t)row * 2048 + tid * 8;
        *(float4*)yp = make_float4(y[0], y[1], y[2], y[3]);
        *(float4*)(yp + 4) = make_float4(y[4], y[5], y[6], y[7]);
    }
}

// ---------------- split fp32 -> (hi, lo) planes (strided) ------------------
__global__ void split_s_kernel(const float* __restrict__ in, int ld, int cols,
                               u16* __restrict__ hi, u16* __restrict__ lo) {
    int idx = (blockIdx.x * 256 + threadIdx.x) * 4;
    int r = idx / cols, c = idx % cols;
    float4 v = *(const float4*)(in + (size_t)r * ld + c);
    ushort4 h, l;
    h.x = f2bf(v.x); l.x = f2bf(v.x - bf2f(h.x));
    h.y = f2bf(v.y); l.y = f2bf(v.y - bf2f(h.y));
    h.z = f2bf(v.z); l.z = f2bf(v.z - bf2f(h.z));
    h.w = f2bf(v.w); l.w = f2bf(v.w - bf2f(h.w));
    *(ushort4*)(hi + idx) = h;
    *(ushort4*)(lo + idx) = l;
}

// ---------------- transpose + split fp32 -----------------------------------
__global__ void split_t_kernel(const float* __restrict__ in, u16* __restrict__ hi,
                               u16* __restrict__ lo, int rows, int cols) {
    __shared__ float t[32][33];
    int bx = blockIdx.x, by = blockIdx.y;
    int lx = threadIdx.x & 31, ly = threadIdx.x >> 5;
    for (int r = ly; r < 32; r += 8)
        t[r][lx] = in[(size_t)(by * 32 + r) * cols + bx * 32 + lx];
    __syncthreads();
    for (int r = ly; r < 32; r += 8) {
        float v = t[lx][r];
        size_t o = (size_t)(bx * 32 + r) * rows + by * 32 + lx;
        u16 h = f2bf(v);
        hi[o] = h;
        lo[o] = f2bf(v - bf2f(h));
    }
}

// ---------------- three 128x128 transpose+splits in one launch -------------
__global__ void split_t3_kernel(const float* __restrict__ i0, u16* __restrict__ h0,
                                u16* __restrict__ l0,
                                const float* __restrict__ i1, u16* __restrict__ h1,
                                u16* __restrict__ l1,
                                const float* __restrict__ i2, u16* __restrict__ h2,
                                u16* __restrict__ l2) {
    __shared__ float t[32][33];
    const float* in; u16* hi; u16* lo;
    switch (blockIdx.z) {
        case 0:  in = i0; hi = h0; lo = l0; break;
        case 1:  in = i1; hi = h1; lo = l1; break;
        default: in = i2; hi = h2; lo = l2; break;
    }
    int bx = blockIdx.x, by = blockIdx.y;
    int lx = threadIdx.x & 31, ly = threadIdx.x >> 5;
    for (int r = ly; r < 32; r += 8)
        t[r][lx] = in[(size_t)(by * 32 + r) * 128 + bx * 32 + lx];
    __syncthreads();
    for (int r = ly; r < 32; r += 8) {
        float v = t[lx][r];
        size_t o = (size_t)(bx * 32 + r) * 128 + by * 32 + lx;
        u16 h = f2bf(v);
        hi[o] = h;
        lo[o] = f2bf(v - bf2f(h));
    }
}

// ---------------- split-bf16 MFMA GEMM (both operands split) ---------------
__global__ __launch_bounds__(256) void gemm_kernel(
    const u16* __restrict__ Ah, const u16* __restrict__ Al, int lda, long aZ, int aDiv,
    const u16* __restrict__ Bh, const u16* __restrict__ Bl, int ldb, long bZ, int bDiv,
    float* __restrict__ C, int ldc, long cZ, int cDiv, int K, float alpha) {
    const int m0 = blockIdx.y * 128, n0 = blockIdx.x * 128;
    const int z = blockIdx.z;
    {
        long ao = (long)(z >> aDiv) * aZ;
        long bo = (long)(z >> bDiv) * bZ;
        Ah += ao; Al += ao; Bh += bo; Bl += bo;
    }
    __shared__ u16 Ash[2][2][128][36];
    __shared__ u16 Bsh[2][2][128][36];

    const int tid = threadIdx.x, lane = tid & 63, wave = tid >> 6;
    const int wr = wave >> 1, wc = wave & 1;
    const int fr = lane & 15, fg8 = (lane >> 4) * 8;
    const int srow = tid >> 2, cc8 = (tid & 3) * 8;

    f32x4 acc[4][4];
#pragma unroll
    for (int m = 0; m < 4; ++m)
#pragma unroll
        for (int n = 0; n < 4; ++n) acc[m][n] = (f32x4)0.0f;

    uint4 rah0, rah1, ral0, ral1, rbh0, rbh1, rbl0, rbl1;
    const size_t aoff0 = (size_t)(m0 + srow) * lda + cc8;
    const size_t aoff1 = aoff0 + (size_t)64 * lda;
    const size_t boff0 = (size_t)(n0 + srow) * ldb + cc8;
    const size_t boff1 = boff0 + (size_t)64 * ldb;

#define G_LOAD(k0) { \
    rah0 = *(const uint4*)(Ah + aoff0 + (k0)); rah1 = *(const uint4*)(Ah + aoff1 + (k0)); \
    ral0 = *(const uint4*)(Al + aoff0 + (k0)); ral1 = *(const uint4*)(Al + aoff1 + (k0)); \
    rbh0 = *(const uint4*)(Bh + boff0 + (k0)); rbh1 = *(const uint4*)(Bh + boff1 + (k0)); \
    rbl0 = *(const uint4*)(Bl + boff0 + (k0)); rbl1 = *(const uint4*)(Bl + boff1 + (k0)); }
#define G_STORE(b) { \
    st8(&Ash[b][0][srow][cc8], rah0); st8(&Ash[b][0][srow + 64][cc8], rah1); \
    st8(&Ash[b][1][srow][cc8], ral0); st8(&Ash[b][1][srow + 64][cc8], ral1); \
    st8(&Bsh[b][0][srow][cc8], rbh0); st8(&Bsh[b][0][srow + 64][cc8], rbh1); \
    st8(&Bsh[b][1][srow][cc8], rbl0); st8(&Bsh[b][1][srow + 64][cc8], rbl1); }

    const int nk = K >> 5;
    G_LOAD(0);
    G_STORE(0);
    __syncthreads();
    int cur = 0;
    for (int ik = 0; ik < nk; ++ik) {
        if (ik + 1 < nk) G_LOAD((ik + 1) << 5);
        bf16x8 bh[4], bl[4];
#pragma unroll
        for (int n = 0; n < 4; ++n) {
            bh[n] = ld16(&Bsh[cur][0][wc * 64 + n * 16 + fr][fg8]);
            bl[n] = ld16(&Bsh[cur][1][wc * 64 + n * 16 + fr][fg8]);
        }
#pragma unroll
        for (int m = 0; m < 4; ++m) {
            bf16x8 ah = ld16(&Ash[cur][0][wr * 64 + m * 16 + fr][fg8]);
            bf16x8 al = ld16(&Ash[cur][1][wr * 64 + m * 16 + fr][fg8]);
#pragma unroll
            for (int n = 0; n < 4; ++n) {
                acc[m][n] = __builtin_amdgcn_mfma_f32_16x16x32_bf16(ah, bh[n], acc[m][n], 0, 0, 0);
                acc[m][n] = __builtin_amdgcn_mfma_f32_16x16x32_bf16(ah, bl[n], acc[m][n], 0, 0, 0);
                acc[m][n] = __builtin_amdgcn_mfma_f32_16x16x32_bf16(al, bh[n], acc[m][n], 0, 0, 0);
            }
        }
        if (ik + 1 < nk) G_STORE(cur ^ 1);
        __syncthreads();
        cur ^= 1;
    }
    const long co = (long)(z >> cDiv) * cZ;
#pragma unroll
    for (int m = 0; m < 4; ++m) {
        int row_b = m0 + wr * 64 + m * 16 + (fg8 >> 1);
#pragma unroll
        for (int n = 0; n < 4; ++n) {
            int col = n0 + wc * 64 + n * 16 + fr;
#pragma unroll
            for (int j = 0; j < 4; ++j)
                C[co + (long)(row_b + j) * ldc + col] = alpha * acc[m][n][j];
        }
    }
#undef G_LOAD
#undef G_STORE
}

// ---------------- merged Q/K head-transform GEMM with fused RoPE -----------
__global__ __launch_bounds__(256) void gemm_qk_kernel(
    const float* __restrict__ QKVf,
    const float* __restrict__ cosp, const float* __restrict__ sinp,
    const u16* __restrict__ iTk_h, const u16* __restrict__ iTk_l,
    const u16* __restrict__ TkT_h, const u16* __restrict__ TkT_l,
    float* __restrict__ q2f, float* __restrict__ k2f) {
    const int m0 = blockIdx.y * 128;
    const int z = blockIdx.z;
    const bool isQ = (z < 16);
    const float* A = QKVf + (isQ ? z * 128 : 2048 + (z - 16) * 128);
    const u16* Bh = isQ ? iTk_h : TkT_h;
    const u16* Bl = isQ ? iTk_l : TkT_l;
    float* C = isQ ? (q2f + z * 128) : (k2f + (z - 16) * 128);
    const int ldc = isQ ? 2048 : 1024;
    const int lda = 4096, ldb = 128, K = 128;

    __shared__ u16 Ash[2][2][128][36];
    __shared__ u16 Bsh[2][2][128][36];
    const int tid = threadIdx.x, lane = tid & 63, wave = tid >> 6;
    const int wr = wave >> 1, wc = wave & 1;
    const int fr = lane & 15, fg8 = (lane >> 4) * 8;
    const int srow = tid >> 2, cc8 = (tid & 3) * 8;

    f32x4 acc[4][4];
#pragma unroll
    for (int m = 0; m < 4; ++m)
#pragma unroll
        for (int n = 0; n < 4; ++n) acc[m][n] = (f32x4)0.0f;

    float4 a00, a01, a10, a11;
    uint4 rbh0, rbh1, rbl0, rbl1;
    const size_t aoff0 = (size_t)(m0 + srow) * lda + cc8;
    const size_t aoff1 = aoff0 + (size_t)64 * lda;
    const size_t boff0 = (size_t)srow * ldb + cc8;
    const size_t boff1 = boff0 + (size_t)64 * ldb;
    const size_t coff0 = (size_t)(m0 + srow) * 128 + cc8;
    const size_t coff1 = coff0 + (size_t)64 * 128;

#define ROPE4(va, vb, vc4, vs4, sg) make_float4( \
    (va).x * (vc4).x + (sg) * (vb).x * (vs4).x, \
    (va).y * (vc4).y + (sg) * (vb).y * (vs4).y, \
    (va).z * (vc4).z + (sg) * (vb).z * (vs4).z, \
    (va).w * (vc4).w + (sg) * (vb).w * (vs4).w)
#define GQ_LOAD(k0) { \
    const int d0_ = (k0) + cc8; \
    const int po_ = (d0_ < 64) ? 64 : -64; \
    const float sg_ = (d0_ < 64) ? -1.0f : 1.0f; \
    float4 ax0 = *(const float4*)(A + aoff0 + (k0)); \
    float4 ax1 = *(const float4*)(A + aoff0 + (k0) + 4); \
    float4 ay0 = *(const float4*)(A + aoff0 + (k0) + po_); \
    float4 ay1 = *(const float4*)(A + aoff0 + (k0) + 4 + po_); \
    float4 pc0 = *(const float4*)(cosp + coff0 + (k0)); \
    float4 pc1 = *(const float4*)(cosp + coff0 + (k0) + 4); \
    float4 ps0 = *(const float4*)(sinp + coff0 + (k0)); \
    float4 ps1 = *(const float4*)(sinp + coff0 + (k0) + 4); \
    a00 = ROPE4(ax0, ay0, pc0, ps0, sg_); a01 = ROPE4(ax1, ay1, pc1, ps1, sg_); \
    float4 bx0 = *(const float4*)(A + aoff1 + (k0)); \
    float4 bx1 = *(const float4*)(A + aoff1 + (k0) + 4); \
    float4 by0 = *(const float4*)(A + aoff1 + (k0) + po_); \
    float4 by1 = *(const float4*)(A + aoff1 + (k0) + 4 + po_); \
    float4 qc0 = *(const float4*)(cosp + coff1 + (k0)); \
    float4 qc1 = *(const float4*)(cosp + coff1 + (k0) + 4); \
    float4 qs0 = *(const float4*)(sinp + coff1 + (k0)); \
    float4 qs1 = *(const float4*)(sinp + coff1 + (k0) + 4); \
    a10 = ROPE4(bx0, by0, qc0, qs0, sg_); a11 = ROPE4(bx1, by1, qc1, qs1, sg_); \
    rbh0 = *(const uint4*)(Bh + boff0 + (k0)); rbh1 = *(const uint4*)(Bh + boff1 + (k0)); \
    rbl0 = *(const uint4*)(Bl + boff0 + (k0)); rbl1 = *(const uint4*)(Bl + boff1 + (k0)); }
#define GQ_STORE(b) { \
    uint4 h0_, l0_, h1_, l1_; \
    cvt8(a00, a01, h0_, l0_); cvt8(a10, a11, h1_, l1_); \
    st8(&Ash[b][0][srow][cc8], h0_); st8(&Ash[b][0][srow + 64][cc8], h1_); \
    st8(&Ash[b][1][srow][cc8], l0_); st8(&Ash[b][1][srow + 64][cc8], l1_); \
    st8(&Bsh[b][0][srow][cc8], rbh0); st8(&Bsh[b][0][srow + 64][cc8], rbh1); \
    st8(&Bsh[b][1][srow][cc8], rbl0); st8(&Bsh[b][1][srow + 64][cc8], rbl1); }

    const int nk = K >> 5;
    GQ_LOAD(0);
    GQ_STORE(0);
    __syncthreads();
    int cur = 0;
    for (int ik = 0; ik < nk; ++ik) {
        if (ik + 1 < nk) GQ_LOAD((ik + 1) << 5);
        bf16x8 bh[4], bl[4];
#pragma unroll
        for (int n = 0; n < 4; ++n) {
            bh[n] = ld16(&Bsh[cur][0][wc * 64 + n * 16 + fr][fg8]);
            bl[n] = ld16(&Bsh[cur][1][wc * 64 + n * 16 + fr][fg8]);
        }
#pragma unroll
        for (int m = 0; m < 4; ++m) {
            bf16x8 ah = ld16(&Ash[cur][0][wr * 64 + m * 16 + fr][fg8]);
            bf16x8 al = ld16(&Ash[cur][1][wr * 64 + m * 16 + fr][fg8]);
#pragma unroll
            for (int n = 0; n < 4; ++n) {
                acc[m][n] = __builtin_amdgcn_mfma_f32_16x16x32_bf16(ah, bh[n], acc[m][n], 0, 0, 0);
                acc[m][n] = __builtin_amdgcn_mfma_f32_16x16x32_bf16(ah, bl[n], acc[m][n], 0, 0, 0);
                acc[m][n] = __builtin_amdgcn_mfma_f32_16x16x32_bf16(al, bh[n], acc[m][n], 0, 0, 0);
            }
        }
        if (ik + 1 < nk) GQ_STORE(cur ^ 1);
        __syncthreads();
        cur ^= 1;
    }
#pragma unroll
    for (int m = 0; m < 4; ++m) {
        int row_b = m0 + wr * 64 + m * 16 + (fg8 >> 1);
#pragma unroll
        for (int n = 0; n < 4; ++n) {
            int col = wc * 64 + n * 16 + fr;
#pragma unroll
            for (int j = 0; j < 4; ++j)
                C[(long)(row_b + j) * ldc + col] = acc[m][n][j];
        }
    }
#undef GQ_LOAD
#undef GQ_STORE
#undef ROPE4
}

// ---------------- o2 GEMM with fused split-K combine on A ------------------
__global__ __launch_bounds__(256) void gemm_o2_kernel(
    const float* __restrict__ o01, const float* __restrict__ ml,
    const u16* __restrict__ Bh, const u16* __restrict__ Bl,
    float* __restrict__ C) {
    const int m0 = blockIdx.y * 128;
    const int z = blockIdx.z;
    const int ldb = 128, K = 128, ldc = 2048;
    __shared__ u16 Ash[2][2][128][36];
    __shared__ u16 Bsh[2][2][128][36];
    const int tid = threadIdx.x, lane = tid & 63, wave = tid >> 6;
    const int wr = wave >> 1, wc = wave & 1;
    const int fr = lane & 15, fg8 = (lane >> 4) * 8;
    const int srow = tid >> 2, cc8 = (tid & 3) * 8;

    f32x4 acc[4][4];
#pragma unroll
    for (int m = 0; m < 4; ++m)
#pragma unroll
        for (int n = 0; n < 4; ++n) acc[m][n] = (f32x4)0.0f;

    const int rs0 = z * 2048 + m0 + srow;
    const int rs1 = rs0 + 64;
    float w0a, w1a, w0b, w1b;
    {
        float ma0 = ml[rs0], la0 = ml[32768 + rs0];
        float ma1 = ml[65536 + rs0], la1 = ml[98304 + rs0];
        float mm = fmaxf(ma0, ma1);
        float e0 = exp2f(ma0 - mm), e1 = exp2f(ma1 - mm);
        float linv = 1.0f / (la0 * e0 + la1 * e1);
        w0a = e0 * linv; w1a = e1 * linv;
        float mb0 = ml[rs1], lb0 = ml[32768 + rs1];
        float mb1 = ml[65536 + rs1], lb1 = ml[98304 + rs1];
        float mmb = fmaxf(mb0, mb1);
        float f0 = exp2f(mb0 - mmb), f1 = exp2f(mb1 - mmb);
        float linvb = 1.0f / (lb0 * f0 + lb1 * f1);
        w0b = f0 * linvb; w1b = f1 * linvb;
    }
    const float* A0 = o01 + (size_t)rs0 * 128 + cc8;
    const float* A1 = o01 + 4194304 + (size_t)rs0 * 128 + cc8;
    const float* B0 = o01 + (size_t)rs1 * 128 + cc8;
    const float* B1 = o01 + 4194304 + (size_t)rs1 * 128 + cc8;

    float4 a00, a01, a10, a11;
    uint4 rbh0, rbh1, rbl0, rbl1;
    const size_t boff0 = (size_t)srow * ldb + cc8;
    const size_t boff1 = boff0 + (size_t)64 * ldb;

#define CMB4(p, q, w0_, w1_) make_float4( \
    (p).x * (w0_) + (q).x * (w1_), (p).y * (w0_) + (q).y * (w1_), \
    (p).z * (w0_) + (q).z * (w1_), (p).w * (w0_) + (q).w * (w1_))
#define GO_LOAD(k0) { \
    float4 p0 = *(const float4*)(A0 + (k0)), p1 = *(const float4*)(A1 + (k0)); \
    float4 p2 = *(const float4*)(A0 + (k0) + 4), p3 = *(const float4*)(A1 + (k0) + 4); \
    a00 = CMB4(p0, p1, w0a, w1a); a01 = CMB4(p2, p3, w0a, w1a); \
    float4 q0 = *(const float4*)(B0 + (k0)), q1 = *(const float4*)(B1 + (k0)); \
    float4 q2 = *(const float4*)(B0 + (k0) + 4), q3 = *(const float4*)(B1 + (k0) + 4); \
    a10 = CMB4(q0, q1, w0b, w1b); a11 = CMB4(q2, q3, w0b, w1b); \
    rbh0 = *(const uint4*)(Bh + boff0 + (k0)); rbh1 = *(const uint4*)(Bh + boff1 + (k0)); \
    rbl0 = *(const uint4*)(Bl + boff0 + (k0)); rbl1 = *(const uint4*)(Bl + boff1 + (k0)); }
#define GO_STORE(b) { \
    uint4 h0_, l0_, h1_, l1_; \
    cvt8(a00, a01, h0_, l0_); cvt8(a10, a11, h1_, l1_); \
    st8(&Ash[b][0][srow][cc8], h0_); st8(&Ash[b][0][srow + 64][cc8], h1_); \
    st8(&Ash[b][1][srow][cc8], l0_); st8(&Ash[b][1][srow + 64][cc8], l1_); \
    st8(&Bsh[b][0][srow][cc8], rbh0); st8(&Bsh[b][0][srow + 64][cc8], rbh1); \
    st8(&Bsh[b][1][srow][cc8], rbl0); st8(&Bsh[b][1][srow + 64][cc8], rbl1); }

    const int nk = K >> 5;
    GO_LOAD(0);
    GO_STORE(0);
    __syncthreads();
    int cur = 0;
    for (int ik = 0; ik < nk; ++ik) {
        if (ik + 1 < nk) GO_LOAD((ik + 1) << 5);
        bf16x8 bh[4], bl[4];
#pragma unroll
        for (int n = 0; n < 4; ++n) {
            bh[n] = ld16(&Bsh[cur][0][wc * 64 + n * 16 + fr][fg8]);
            bl[n] = ld16(&Bsh[cur][1][wc * 64 + n * 16 + fr][fg8]);
        }
#pragma unroll
        for (int m = 0; m < 4; ++m) {
            bf16x8 ah = ld16(&Ash[cur][0][wr * 64 + m * 16 + fr][fg8]);
            bf16x8 al = ld16(&Ash[cur][1][wr * 64 + m * 16 + fr][fg8]);
#pragma unroll
            for (int n = 0; n < 4; ++n) {
                acc[m][n] = __builtin_amdgcn_mfma_f32_16x16x32_bf16(ah, bh[n], acc[m][n], 0, 0, 0);
                acc[m][n] = __builtin_amdgcn_mfma_f32_16x16x32_bf16(ah, bl[n], acc[m][n], 0, 0, 0);
                acc[m][n] = __builtin_amdgcn_mfma_f32_16x16x32_bf16(al, bh[n], acc[m][n], 0, 0, 0);
            }
        }
        if (ik + 1 < nk) GO_STORE(cur ^ 1);
        __syncthreads();
        cur ^= 1;
    }
#pragma unroll
    for (int m = 0; m < 4; ++m) {
        int row_b = m0 + wr * 64 + m * 16 + (fg8 >> 1);
#pragma unroll
        for (int n = 0; n < 4; ++n) {
            int col = wc * 64 + n * 16 + fr;
#pragma unroll
            for (int j = 0; j < 4; ++j)
                C[(long)(row_b + j) * ldc + z * 128 + col] = acc[m][n][j];
        }
    }
#undef GO_LOAD
#undef GO_STORE
#undef CMB4
}

// ---------------- int-bf16 MFMA GEMM (z-batched) ---------------------------
__global__ __launch_bounds__(256) void gemm_int_kernel(
    const u16* __restrict__ A, int lda, const float* __restrict__ sa,
    const u16* __restrict__ B, int ldb, const float* __restrict__ sb,
    float* __restrict__ C, int ldc, long aZ, long bZ, long cZ, int K) {
    const int m0 = blockIdx.y * 128, n0 = blockIdx.x * 128;
    const int z = blockIdx.z;
    A += (long)z * aZ; B += (long)z * bZ; C += (long)z * cZ;
    __shared__ u16 Ash[2][128][36];
    __shared__ u16 Bsh[2][128][36];
    const int tid = threadIdx.x, lane = tid & 63, wave = tid >> 6;
    const int wr = wave >> 1, wc = wave & 1;
    const int fr = lane & 15, fg8 = (lane >> 4) * 8;
    const int srow = tid >> 2, cc8 = (tid & 3) * 8;
    f32x4 acc[4][4];
#pragma unroll
    for (int m = 0; m < 4; ++m)
#pragma unroll
        for (int n = 0; n < 4; ++n) acc[m][n] = (f32x4)0.0f;

    uint4 ra0, ra1, rb0, rb1;
    const size_t aoff0 = (size_t)(m0 + srow) * lda + cc8;
    const size_t aoff1 = aoff0 + (size_t)64 * lda;
    const size_t boff0 = (size_t)(n0 + srow) * ldb + cc8;
    const size_t boff1 = boff0 + (size_t)64 * ldb;
#define GI_LOAD(k0) { \
    ra0 = *(const uint4*)(A + aoff0 + (k0)); ra1 = *(const uint4*)(A + aoff1 + (k0)); \
    rb0 = *(const uint4*)(B + boff0 + (k0)); rb1 = *(const uint4*)(B + boff1 + (k0)); }
#define GI_STORE(b) { \
    st8(&Ash[b][srow][cc8], ra0); st8(&Ash[b][srow + 64][cc8], ra1); \
    st8(&Bsh[b][srow][cc8], rb0); st8(&Bsh[b][srow + 64][cc8], rb1); }
    const int nk = K >> 5;
    GI_LOAD(0);
    GI_STORE(0);
    __syncthreads();
    int cur = 0;
    for (int ik = 0; ik < nk; ++ik) {
        if (ik + 1 < nk) GI_LOAD((ik + 1) << 5);
        bf16x8 bfr[4];
#pragma unroll
        for (int n = 0; n < 4; ++n)
            bfr[n] = ld16(&Bsh[cur][wc * 64 + n * 16 + fr][fg8]);
#pragma unroll
        for (int m = 0; m < 4; ++m) {
            bf16x8 ah = ld16(&Ash[cur][wr * 64 + m * 16 + fr][fg8]);
#pragma unroll
            for (int n = 0; n < 4; ++n)
                acc[m][n] = __builtin_amdgcn_mfma_f32_16x16x32_bf16(ah, bfr[n], acc[m][n], 0, 0, 0);
        }
        if (ik + 1 < nk) GI_STORE(cur ^ 1);
        __syncthreads();
        cur ^= 1;
    }
#pragma unroll
    for (int m = 0; m < 4; ++m) {
        int row_b = m0 + wr * 64 + m * 16 + (fg8 >> 1);
#pragma unroll
        for (int n = 0; n < 4; ++n) {
            int col = n0 + wc * 64 + n * 16 + fr;
            float sc = sb[col];
#pragma unroll
            for (int j = 0; j < 4; ++j)
                C[(long)(row_b + j) * ldc + col] = acc[m][n][j] * sa[row_b + j] * sc;
        }
    }
#undef GI_LOAD
#undef GI_STORE
}

// ---------------- per-row fake_quant (wide rows) ---------------------------
__global__ void rowquant_int_kernel(const float* __restrict__ x, u16* __restrict__ qi,
                                    float* __restrict__ sc, int cols) {
    __shared__ float red[256];
    int row = blockIdx.x, tid = threadIdx.x;
    const float* p = x + (size_t)row * cols;
    u16* q = qi + (size_t)row * cols;
    float m = 0.0f;
    for (int j = tid; j < cols; j += 256) m = fmaxf(m, fabsf(p[j]));
    red[tid] = m; __syncthreads();
    for (int s = 128; s > 0; s >>= 1) {
        if (tid < s) red[tid] = fmaxf(red[tid], red[tid + s]);
        __syncthreads();
    }
    float scale = fmaxf(red[0] / 127.0f, 1e-8f);
    if (tid == 0) sc[row] = scale;
    for (int j = tid; j < cols; j += 256) {
        float v = rintf(p[j] / scale);
        v = fminf(fmaxf(v, -127.0f), 127.0f);
        q[j] = f2bf(v);
    }
}

// ---------------- dual per-row fake_quant (two tensors, one launch) --------
__global__ void rowquant2_kernel(const float* __restrict__ x0, u16* __restrict__ q0,
                                 float* __restrict__ s0,
                                 const float* __restrict__ x1, u16* __restrict__ q1,
                                 float* __restrict__ s1) {
    __shared__ float red[256];
    int bid = blockIdx.x, tid = threadIdx.x;
    const float* p; u16* q; float* sc; int row;
    if (bid < 2048) { p = x0; q = q0; sc = s0; row = bid; }
    else            { p = x1; q = q1; sc = s1; row = bid - 2048; }
    p += (size_t)row * 2048;
    q += (size_t)row * 2048;
    float m = 0.0f;
    for (int j = tid; j < 2048; j += 256) m = fmaxf(m, fabsf(p[j]));
    red[tid] = m; __syncthreads();
    for (int s = 128; s > 0; s >>= 1) {
        if (tid < s) red[tid] = fmaxf(red[tid], red[tid + s]);
        __syncthreads();
    }
    float scale = fmaxf(red[0] / 127.0f, 1e-8f);
    if (tid == 0) sc[row] = scale;
    for (int j = tid; j < 2048; j += 256) {
        float v = rintf(p[j] / scale);
        v = fminf(fmaxf(v, -127.0f), 127.0f);
        q[j] = f2bf(v);
    }
}

// ---------------- per-row fake_quant, 128-col rows, 1 wave/row -------------
__global__ void rowquant_w_kernel(const float* __restrict__ x, u16* __restrict__ qi,
                                  float* __restrict__ sc) {
    int row = blockIdx.x * 4 + (threadIdx.x >> 6);
    int lane = threadIdx.x & 63;
    const float* p = x + (size_t)row * 128;
    float2 v = *(const float2*)(p + lane * 2);
    float m = fmaxf(fabsf(v.x), fabsf(v.y));
#pragma unroll
    for (int off = 1; off < 64; off <<= 1) m = fmaxf(m, __shfl_xor(m, off));
    float scale = fmaxf(m / 127.0f, 1e-8f);
    if (lane == 0) sc[row] = scale;
    float a = rintf(v.x / scale), b = rintf(v.y / scale);
    a = fminf(fmaxf(a, -127.0f), 127.0f);
    b = fminf(fmaxf(b, -127.0f), 127.0f);
    unsigned pk = f2bf(a) | ((unsigned)f2bf(b) << 16);
    *(unsigned*)(qi + (size_t)row * 128 + lane * 2) = pk;
}

// ---------------- fused V fake_quant + transpose ---------------------------
__global__ __launch_bounds__(256) void quantT_v_kernel(
    const float* __restrict__ QKVf, u16* __restrict__ vTi, float* __restrict__ vs) {
    __shared__ u16 tile[128][72];
    const int st = blockIdx.x, g = blockIdx.y;
    const int t = threadIdx.x;
    const int sl = t >> 2, dc = (t & 3) * 32;
    const int s = st * 64 + sl;
    const float* p = QKVf + (size_t)s * 4096 + 3072 + g * 128 + dc;
    float4 vr[8];
    float m = 0.0f;
#pragma unroll
    for (int q = 0; q < 8; ++q) {
        vr[q] = *(const float4*)(p + q * 4);
        m = fmaxf(m, fmaxf(fmaxf(fabsf(vr[q].x), fabsf(vr[q].y)),
                           fmaxf(fabsf(vr[q].z), fabsf(vr[q].w))));
    }
    m = fmaxf(m, __shfl_xor(m, 1));
    m = fmaxf(m, __shfl_xor(m, 2));
    float scale = fmaxf(m / 127.0f, 1e-8f);
    if ((t & 3) == 0) vs[s * 8 + g] = scale;
#pragma unroll
    for (int q = 0; q < 8; ++q) {
        float vv[4] = {vr[q].x, vr[q].y, vr[q].z, vr[q].w};
#pragma unroll
        for (int e = 0; e < 4; ++e) {
            float qv = rintf(vv[e] / scale);
            qv = fminf(fmaxf(qv, -127.0f), 127.0f);
            tile[dc + q * 4 + e][sl] = f2bf(qv);
        }
    }
    __syncthreads();
    const int d = t >> 1, sc0 = (t & 1) * 32;
    u16* dst = vTi + (size_t)(g * 128 + d) * 2048 + st * 64 + sc0;
#pragma unroll
    for (int q = 0; q < 4; ++q) {
        u16 tmp[8];
#pragma unroll
        for (int e = 0; e < 8; ++e) tmp[e] = tile[d][sc0 + q * 8 + e];
        uint4 v;
        v.x = tmp[0] | ((unsigned)tmp[1] << 16); v.y = tmp[2] | ((unsigned)tmp[3] << 16);
        v.z = tmp[4] | ((unsigned)tmp[5] << 16); v.w = tmp[6] | ((unsigned)tmp[7] << 16);
        *(uint4*)(dst + q * 8) = v;
    }
}

// ---------------- elementwise add ------------------------------------------
__global__ void add2_kernel(const float* __restrict__ a, const float* __restrict__ b,
                            float* __restrict__ o) {
    int i = (blockIdx.x * 256 + threadIdx.x) * 4;
    float4 x = *(const float4*)(a + i);
    float4 y = *(const float4*)(b + i);
    x.x += y.x; x.y += y.y; x.z += y.z; x.w += y.w;
    *(float4*)(o + i) = x;
}

// ---------------- flash attention v5 (unchanged) ---------------------------
__global__ __launch_bounds__(256, 2) void flash_kernel(
    const float* __restrict__ q2f,
    const u16* __restrict__ k2i, const float* __restrict__ ksc,
    const u16* __restrict__ vTi, const float* __restrict__ vsc,
    float* __restrict__ obuf, float* __restrict__ mlbuf) {
    const int h = blockIdx.x, part = blockIdx.y, qt = 31 - blockIdx.z, g = h >> 1;
    __shared__ u16 Ksh[2][64 * 128];
    __shared__ u16 Vsh[2][128 * 64];
    __shared__ u16 Psh[4][16 * 64];
    __shared__ float Kss[2][64];
    __shared__ float Vss[2][64];

    const int tid = threadIdx.x, lane = tid & 63, w = tid >> 6;
    const int lc = lane & 15, lg = lane >> 4;
    const float scale = 0.08838834764831845f;
    const float LOG2E = 1.4426950408889634f;
    const float THR = 10.0f;

    bf16x8 qh[4], ql[4];
    {
        int s = qt * 64 + w * 16 + lc;
        const float* qp = q2f + (size_t)s * 2048 + h * 128 + lg * 8;
#pragma unroll
        for (int kk = 0; kk < 4; ++kk) {
            float4 v0 = *(const float4*)(qp + kk * 32);
            float4 v1 = *(const float4*)(qp + kk * 32 + 4);
            float vv[8] = {v0.x, v0.y, v0.z, v0.w, v1.x, v1.y, v1.z, v1.w};
#pragma unroll
            for (int e = 0; e < 8; ++e) {
                float x = vv[e] * scale;
                u16 hh = f2bf(x);
                qh[kk][e] = (short)hh;
                ql[kk][e] = (short)f2bf(x - bf2f(hh));
            }
        }
    }

    f32x4 acc_o[8];
#pragma unroll
    for (int nn = 0; nn < 8; ++nn) acc_o[nn] = (f32x4)0.0f;
    float mj = -1e30f, lj = 0.0f;

    const int p0cnt = (qt + 2) >> 1;
    const int tn = (part == 0) ? p0cnt : (qt + 1 - p0cnt);
    const int t0 = (part == 0) ? 0 : p0cnt;

    const int kr = tid >> 2, kc = tid & 3;
    const int vd = tid >> 1, vc0 = (tid & 1) * 4;
    uint4 kg0, kg1, kg2, kg3, vg0, vg1, vg2, vg3;
    float sreg = 0.0f;

#define STAGE_LOAD(tg) { \
    const int j0_ = (tg) * 64; \
    const u16* kp_ = k2i + (size_t)(j0_ + kr) * 1024 + g * 128; \
    kg0 = *(const uint4*)(kp_ + kc * 8); \
    kg1 = *(const uint4*)(kp_ + (kc + 4) * 8); \
    kg2 = *(const uint4*)(kp_ + (kc + 8) * 8); \
    kg3 = *(const uint4*)(kp_ + (kc + 12) * 8); \
    const u16* vp_ = vTi + (size_t)(g * 128 + vd) * 2048 + j0_; \
    vg0 = *(const uint4*)(vp_ + vc0 * 8); \
    vg1 = *(const uint4*)(vp_ + (vc0 + 1) * 8); \
    vg2 = *(const uint4*)(vp_ + (vc0 + 2) * 8); \
    vg3 = *(const uint4*)(vp_ + (vc0 + 3) * 8); \
    if (tid < 64) sreg = ksc[(j0_ + tid) * 8 + g] * LOG2E; \
    else if (tid < 128) sreg = vsc[(j0_ + tid - 64) * 8 + g]; }

#define STAGE_WRITE(b) { \
    *(uint4*)(&Ksh[b][kr * 128 + ((kc ^ (kr & 7)) << 3)]) = kg0; \
    *(uint4*)(&Ksh[b][kr * 128 + (((kc + 4) ^ (kr & 7)) << 3)]) = kg1; \
    *(uint4*)(&Ksh[b][kr * 128 + (((kc + 8) ^ (kr & 7)) << 3)]) = kg2; \
    *(uint4*)(&Ksh[b][kr * 128 + (((kc + 12) ^ (kr & 7)) << 3)]) = kg3; \
    *(uint4*)(&Vsh[b][vd * 64 + ((vc0 ^ (vd & 7)) << 3)]) = vg0; \
    *(uint4*)(&Vsh[b][vd * 64 + (((vc0 + 1) ^ (vd & 7)) << 3)]) = vg1; \
    *(uint4*)(&Vsh[b][vd * 64 + (((vc0 + 2) ^ (vd & 7)) << 3)]) = vg2; \
    *(uint4*)(&Vsh[b][vd * 64 + (((vc0 + 3) ^ (vd & 7)) << 3)]) = vg3; \
    if (tid < 64) Kss[b][tid] = sreg; \
    else if (tid < 128) Vss[b][tid - 64] = sreg; }

    if (tn > 0) {
        STAGE_LOAD(t0);
        STAGE_WRITE(0);
    }
    __syncthreads();
    for (int t = 0; t < tn; ++t) {
        const int cur = t & 1;
        const int tg = t0 + t;
        if (t + 1 < tn) STAGE_LOAD(t0 + t + 1);

        f32x4 accs[4];
#pragma unroll
        for (int n = 0; n < 4; ++n) accs[n] = (f32x4)0.0f;
#pragma unroll
        for (int n = 0; n < 4; ++n) {
#pragma unroll
            for (int kk = 0; kk < 4; ++kk) {
                bf16x8 kf = ld16(&Ksh[cur][(n * 16 + lc) * 128 + (((kk * 4 + lg) ^ (lc & 7)) << 3)]);
                accs[n] = __builtin_amdgcn_mfma_f32_16x16x32_bf16(kf, qh[kk], accs[n], 0, 0, 0);
                accs[n] = __builtin_amdgcn_mfma_f32_16x16x32_bf16(kf, ql[kk], accs[n], 0, 0, 0);
            }
        }
#pragma unroll
        for (int n = 0; n < 4; ++n)
#pragma unroll
            for (int j = 0; j < 4; ++j)
                accs[n][j] *= Kss[cur][n * 16 + lg * 4 + j];
        if (tg == qt) {
            int qg = qt * 64 + w * 16 + lc;
#pragma unroll
            for (int n = 0; n < 4; ++n)
#pragma unroll
                for (int j = 0; j < 4; ++j) {
                    int kgl = tg * 64 + n * 16 + lg * 4 + j;
                    if (kgl > qg) accs[n][j] = -3.0e38f;
                }
        }

        float pm = accs[0][0];
#pragma unroll
        for (int n = 0; n < 4; ++n)
#pragma unroll
            for (int j = 0; j < 4; ++j) pm = fmaxf(pm, accs[n][j]);
        pm = fmaxf(pm, __shfl_xor(pm, 16));
        pm = fmaxf(pm, __shfl_xor(pm, 32));
        bool need = pm > mj + THR;
        float mn = need ? pm : mj;
        float sf = need ? exp2f(mj - mn) : 1.0f;
        mj = mn;
        if (__any(need)) {
            float sfj[4];
#pragma unroll
            for (int j = 0; j < 4; ++j) sfj[j] = __shfl(sf, lg * 4 + j);
#pragma unroll
            for (int nn = 0; nn < 8; ++nn)
#pragma unroll
                for (int j = 0; j < 4; ++j) acc_o[nn][j] *= sfj[j];
        }
        float rowsum = 0.0f;
#pragma unroll
        for (int n = 0; n < 4; ++n)
#pragma unroll
            for (int j = 0; j < 4; ++j) {
                float p = exp2f(accs[n][j] - mj);
                accs[n][j] = p;
                rowsum += p;
            }
        rowsum += __shfl_xor(rowsum, 16);
        rowsum += __shfl_xor(rowsum, 32);
        lj = lj * sf + rowsum;

#pragma unroll
        for (int n = 0; n < 4; ++n)
#pragma unroll
            for (int jp = 0; jp < 2; ++jp) {
                int k = n * 16 + lg * 4 + jp * 2;
                unsigned val = f2bf(accs[n][jp * 2] * Vss[cur][k]) |
                               ((unsigned)f2bf(accs[n][jp * 2 + 1] * Vss[cur][k + 1]) << 16);
                int cch = k >> 3;
                *(unsigned*)(&Psh[w][lc * 64 + ((cch ^ (lc & 7)) << 3) + (k & 7)]) = val;
            }
        bf16x8 pf[2];
#pragma unroll
        for (int kk = 0; kk < 2; ++kk)
            pf[kk] = ld16(&Psh[w][lc * 64 + (((kk * 4 + lg) ^ (lc & 7)) << 3)]);

#pragma unroll
        for (int nn = 0; nn < 8; ++nn) {
            int d = nn * 16 + lc;
#pragma unroll
            for (int kk = 0; kk < 2; ++kk) {
                bf16x8 vf = ld16(&Vsh[cur][d * 64 + (((kk * 4 + lg) ^ (d & 7)) << 3)]);
                acc_o[nn] = __builtin_amdgcn_mfma_f32_16x16x32_bf16(pf[kk], vf, acc_o[nn], 0, 0, 0);
            }
        }
        if (t + 1 < tn) STAGE_WRITE(cur ^ 1);
        __syncthreads();
    }
#undef STAGE_LOAD
#undef STAGE_WRITE

    float* op = obuf + (size_t)part * 4194304 + ((size_t)h * 2048 + qt * 64 + w * 16) * 128;
#pragma unroll
    for (int nn = 0; nn < 8; ++nn)
#pragma unroll
        for (int j = 0; j < 4; ++j)
            op[(lg * 4 + j) * 128 + nn * 16 + lc] = acc_o[nn][j];
    if (lg == 0) {
        int rs = h * 2048 + qt * 64 + w * 16 + lc;
        mlbuf[part * 65536 + rs] = mj;
        mlbuf[part * 65536 + 32768 + rs] = lj;
    }
}

// ===========================================================================
extern "C" void kernel_launch(void* const* d_in, const int* in_sizes, int n_in,
                              void* d_out, int out_size, void* d_ws, size_t ws_size,
                              hipStream_t stream) {
    const float* hidden = (const float*)d_in[0];
    const float* cosp   = (const float*)d_in[1];
    const float* sinp   = (const float*)d_in[2];
    const float* Wq     = (const float*)d_in[3];
    const float* Wk     = (const float*)d_in[4];
    const float* Wv     = (const float*)d_in[5];
    const float* Wo     = (const float*)d_in[6];
    const float* Lp     = (const float*)d_in[7];
    const float* Rp     = (const float*)d_in[8];
    const float* diag   = (const float*)d_in[9];
    const float* Tkp    = (const float*)d_in[10];
    const float* Tvp    = (const float*)d_in[11];
    float* out = (float*)d_out;

    const size_t MiB = 1ull << 20;
    char* W = (char*)d_ws;
    auto F = [&](size_t mb) { return (float*)(W + mb * MiB); };
    auto U = [&](size_t mb) { return (u16*)(W + mb * MiB); };
    const long HP2 = 2097152;

    float* dsc   = (float*)d_out;
    float* invL  = dsc;
    float* invR  = dsc + 1024;
    float* invTk = dsc + 5120;
    float* invTv = dsc + 21504;
    u16* sm = (u16*)(dsc + 37888);
    u16* invTk_sh = sm;              u16* invTk_sl = sm + 16384;
    u16* TkT_sh   = sm + 2 * 16384;  u16* TkT_sl   = sm + 3 * 16384;
    u16* invTvT_sh= sm + 4 * 16384;  u16* invTvT_sl= sm + 5 * 16384;
    u16* TvT_sh   = sm + 6 * 16384;  u16* TvT_sl   = sm + 7 * 16384;

    float* xs    = F(88);
    float* wqkvs = xs + 2048;
    float* wqs   = wqkvs;
    float* wks   = wqkvs + 2048;
    float* wvs   = wqkvs + 3072;
    float* k2s   = wqkvs + 4096;
    float* vs    = k2s + 16384;
    float* o2s   = vs + 16384;
    float* wos   = o2s + 2048;

    // ---- P0 fused: gj4 + kron(hidden) (4 rows/block) ----
    u16* Xi = U(0);
    p0_kernel<<<516, 1024, 0, stream>>>(Lp, invL, Rp, invR, Tkp, invTk, Tvp, invTv,
                                        hidden, diag, Lp, Rp, Xi, xs);
    split_s_kernel<<<16, 256, 0, stream>>>(invTk, 128, 128, invTk_sh, invTk_sl);
    split_t3_kernel<<<dim3(4, 4, 3), 256, 0, stream>>>(
        Tkp, TkT_sh, TkT_sl, invTv, invTvT_sh, invTvT_sl, Tvp, TvT_sh, TvT_sl);

    // ---- P1: weight kron transforms ----
    u16* WQKVi = U(8);
    u16* WVi   = U(20);
    float* WvP = F(24);
    kron_kernel<1, 1, 1, 1><<<2048, 256, 0, stream>>>(Wq, diag, invL, invR, WQKVi, wqs, 0);
    kron_kernel<1, 1, 1, 1><<<1024, 256, 0, stream>>>(Wk, diag, invL, invR, U(16), wks, 0);
    kron_kernel<1, 1, 0, 1><<<1024, 256, 0, stream>>>(Wv, diag, invL, invR, 0, 0, WvP);

    u16* WVPt_s = U(32);
    split_t_kernel<<<dim3(64, 32), 256, 0, stream>>>(WvP, WVPt_s, WVPt_s + HP2, 1024, 2048);
    float* WVf = F(72);
    gemm_kernel<<<dim3(16, 1, 8), 256, 0, stream>>>(
        TvT_sh, TvT_sl, 128, 0, 0, WVPt_s, WVPt_s + HP2, 1024, 128, 0,
        WVf, 2048, (long)128 * 2048, 0, 128, 1.0f);
    rowquant_int_kernel<<<1024, 256, 0, stream>>>(WVf, WVi, wvs, 2048);

    // ---- P2: merged QKV projection GEMM ----
    float* QKVf = F(40);
    gemm_int_kernel<<<dim3(32, 16), 256, 0, stream>>>(Xi, 2048, xs, WQKVi, 2048, wqkvs,
                                                      QKVf, 4096, 0, 0, 0, 2048);

    // merged Q+K head transforms with fused RoPE (one launch, 384 blocks)
    float* q2f = F(72);
    float* k2f = F(32);
    gemm_qk_kernel<<<dim3(1, 16, 24), 256, 0, stream>>>(
        QKVf, cosp, sinp, invTk_sh, invTk_sl, TkT_sh, TkT_sl, q2f, k2f);
    u16* k2i = U(8);
    rowquant_w_kernel<<<4096, 256, 0, stream>>>(k2f, k2i, k2s);

    // V path
    u16* vTi = U(16);
    quantT_v_kernel<<<dim3(32, 8), 256, 0, stream>>>(QKVf, vTi, vs);

    // ---- P3: flash attention ----
    float* o01 = F(40);
    float* ml  = F(32);
    flash_kernel<<<dim3(16, 2, 32), 256, 0, stream>>>(q2f, k2i, k2s, vTi, vs, o01, ml);

    // ---- P4: o2 = combine(o01) @ inv(Tv) fused; quant; final GEMM ----
    float* o2f = F(16);
    gemm_o2_kernel<<<dim3(1, 16, 16), 256, 0, stream>>>(
        o01, ml, invTvT_sh, invTvT_sl, o2f);
    u16* o2i = U(32);
    u16* Woi = U(40);
    rowquant2_kernel<<<4096, 256, 0, stream>>>(o2f, o2i, o2s, Wo, Woi, wos);
    float* C0 = F(48);
    gemm_int_kernel<<<dim3(16, 16, 2), 256, 0, stream>>>(o2i, 2048, o2s, Woi, 2048, wos,
                                                         C0, 2048, 1024, 1024, 4194304, 1024);
    add2_kernel<<<4096, 256, 0, stream>>>(C0, C0 + 4194304, out);

    (void)in_sizes; (void)n_in; (void)out_size; (void)ws_size;
}